// Round 2
// baseline (530.820 us; speedup 1.0000x reference)
//
#include <hip/hip_runtime.h>
#include <hip/hip_fp16.h>
#include <math.h>

// StackedGCN: N=100000, E=1600000, 128 -> 128 -> 128 -> 64, fp32 in/out.
// FP16 activation pipeline, fp32 MFMA accumulation, dinv prescaled in GEMM
// epilogue. NEW this round: feature-sliced XCD-affine aggregation.
//   GEMM (layers 0/1) writes activations chunk-major: Xc[chunk=8][N][16] fp16.
//   agg128_chunk assigns chunk = blockIdx & 7; with round-robin blockIdx->XCD
//   dispatch each XCD gathers only from its own 3.2 MB slab -> L2-resident
//   random gather (was 190 MB L2-miss traffic / dispatch). csr is re-read
//   once per chunk (streamed nontemporal to avoid evicting the slab).
#define NN 100000
#define EE 1600000
#define NB2 782     // dst buckets: dst>>7 -> 128 nodes per bucket
#define BN 128      // nodes per bucket
#define NPART 512   // scatter_bump blocks
#define CAP 2560    // padded segment capacity (mean 2048, sd ~45 -> +11 sigma)

typedef __attribute__((ext_vector_type(8))) _Float16 half8;
typedef __attribute__((ext_vector_type(4))) float f32x4;
typedef __attribute__((ext_vector_type(4))) unsigned int u32x4;

__device__ inline unsigned short f2h(float x) {
    return __half_as_ushort(__float2half(x));
}
__device__ inline __half2 u2h2(unsigned u) {
    return __builtin_bit_cast(__half2, u);
}
__device__ inline unsigned h22u(__half2 h) {
    return __builtin_bit_cast(unsigned, h);
}

// ---------------- weight prep (+ bcount zero) ----------------

__global__ void prep_weights(const float* __restrict__ W0, const float* __restrict__ W1,
                             const float* __restrict__ W2, unsigned short* __restrict__ Wt0,
                             unsigned short* __restrict__ Wt1, unsigned short* __restrict__ Wt2,
                             int* __restrict__ bcount) {
    int g = blockIdx.x * 256 + threadIdx.x;
    if (g < NB2) bcount[g] = 0;
    if (g < 16384) {
        int n = g >> 7, k = g & 127;
        Wt0[g] = f2h(W0[k * 128 + n]);
    } else if (g < 32768) {
        int i = g - 16384;
        int n = i >> 7, k = i & 127;
        Wt1[i] = f2h(W1[k * 128 + n]);
    } else if (g < 40960) {
        int i = g - 32768;
        int n = i >> 7, k = i & 127;
        Wt2[i] = f2h(W2[k * 64 + n]);
    }
}

// ---------------- CSR build ----------------

__global__ __launch_bounds__(256) void scatter_bump(const int* __restrict__ src,
                                                    const int* __restrict__ dst,
                                                    int* __restrict__ bcount,
                                                    int* __restrict__ P, int e) {
    __shared__ int cnt[NB2];
    __shared__ int basep[NB2];
    __shared__ int cur[NB2];
    int t = threadIdx.x;
    for (int i = t; i < NB2; i += 256) { cnt[i] = 0; cur[i] = 0; }
    __syncthreads();
    int chunk = (e + NPART - 1) / NPART;
    int b0 = blockIdx.x * chunk, b1 = min(e, b0 + chunk);
    for (int i = b0 + t; i < b1; i += 256)
        atomicAdd(&cnt[dst[i] >> 7], 1);
    __syncthreads();
    for (int i = t; i < NB2; i += 256) {
        int c = cnt[i];
        basep[i] = c ? atomicAdd(&bcount[i], c) : 0;
    }
    __syncthreads();
    for (int i = b0 + t; i < b1; i += 256) {  // second read is L2-hot
        int d = dst[i];
        int b = d >> 7;
        int p = basep[b] + atomicAdd(&cur[b], 1);
        P[(size_t)b * CAP + p] = (src[i] << 7) | (d & 127);  // src<2^17: 24 bits
    }
}

__global__ __launch_bounds__(256) void bucket_build(const int* __restrict__ P,
                                                    const int* __restrict__ bcount,
                                                    int2* __restrict__ offs2,
                                                    float* __restrict__ dinv,
                                                    int* __restrict__ csr, int n) {
    __shared__ int cnt[BN];
    __shared__ int sc[BN];
    __shared__ int cur[BN];
    __shared__ int stage[CAP];
    int b = blockIdx.x, t = threadIdx.x;
    int base = b * CAP;
    int count = bcount[b];
    if (t < BN) cnt[t] = 0;
    __syncthreads();
    for (int i = t; i < count; i += 256)
        atomicAdd(&cnt[P[base + i] & 127], 1);
    __syncthreads();
    int v = 0;
    if (t < BN) {
        v = cnt[t];
        sc[t] = v;
    }
    for (int d = 1; d < BN; d <<= 1) {
        __syncthreads();
        int x = (t < BN && t >= d) ? sc[t - d] : 0;
        __syncthreads();
        if (t < BN) sc[t] += x;
    }
    __syncthreads();
    if (t < BN) {
        int myoff = sc[t] - v;
        int node = b * BN + t;
        if (node < n) {
            offs2[node] = make_int2(base + myoff, base + myoff + v);
            dinv[node] = 1.0f / sqrtf((float)(v + 1));  // +1 self-loop
        }
        cur[t] = myoff;
    }
    __syncthreads();
    for (int i = t; i < count; i += 256) {  // second read L2-hot
        int pe = P[base + i];
        int p = atomicAdd(&cur[pe & 127], 1);
        stage[p] = ((unsigned)pe) >> 7;     // p < count <= CAP always
    }
    __syncthreads();
    for (int i = t; i < count; i += 256) csr[base + i] = stage[i];
}

// ---------------- MFMA GEMM (f16) + dinv-prescale epilogue ----------------
// CHUNK_OUT: write Y chunk-major Xc[t][N][16] (t = 16-col MFMA tile index)
// so the aggregation can pin chunk t to one XCD's L2.
template <int DOUT, bool A_IS_F32, bool CHUNK_OUT>
__global__ __launch_bounds__(256) void gemm_mfma(const void* __restrict__ Aptr,
                                                 const unsigned short* __restrict__ Wt,
                                                 const float* __restrict__ dinv,
                                                 unsigned short* __restrict__ Y, int nrows) {
    constexpr int KP = 136;
    constexpr int NT = DOUT / 16;
    __shared__ unsigned short sA[128 * KP];
    __shared__ unsigned short sB[DOUT * KP];
    const int row0 = blockIdx.x * 128;
    const int tid = threadIdx.x;

    for (int i = tid; i < DOUT * 16; i += 256) {
        int n = i >> 4, c = (i & 15) * 8;
        uint4 v = *(const uint4*)(Wt + n * 128 + c);
        *(uint4*)(&sB[n * KP + c]) = v;
    }
    if (A_IS_F32) {
        const float* A = (const float*)Aptr;
        for (int i = tid; i < 128 * 32; i += 256) {
            int r = i >> 5, c = (i & 31) * 4;
            float4 v = make_float4(0.f, 0.f, 0.f, 0.f);
            if (row0 + r < nrows) v = *(const float4*)(A + (size_t)(row0 + r) * 128 + c);
            uint2 o;
            o.x = h22u(__floats2half2_rn(v.x, v.y));
            o.y = h22u(__floats2half2_rn(v.z, v.w));
            *(uint2*)(&sA[r * KP + c]) = o;
        }
    } else {
        const unsigned short* A = (const unsigned short*)Aptr;
        for (int i = tid; i < 128 * 16; i += 256) {
            int r = i >> 4, c = (i & 15) * 8;
            uint4 v = make_uint4(0u, 0u, 0u, 0u);
            if (row0 + r < nrows) v = *(const uint4*)(A + (size_t)(row0 + r) * 128 + c);
            *(uint4*)(&sA[r * KP + c]) = v;
        }
    }
    __syncthreads();

    const int wave = tid >> 6;
    const int lane = tid & 63;
    const int m0 = lane & 15;
    const int kq = (lane >> 4) * 8;

    f32x4 acc[2][NT];
#pragma unroll
    for (int rt = 0; rt < 2; ++rt)
#pragma unroll
        for (int t = 0; t < NT; ++t) acc[rt][t] = (f32x4){0.f, 0.f, 0.f, 0.f};

#pragma unroll
    for (int k0 = 0; k0 < 128; k0 += 32) {
        half8 a0 = *(const half8*)(&sA[(wave * 32 + m0) * KP + k0 + kq]);
        half8 a1 = *(const half8*)(&sA[(wave * 32 + 16 + m0) * KP + k0 + kq]);
#pragma unroll
        for (int t = 0; t < NT; ++t) {
            half8 b = *(const half8*)(&sB[(t * 16 + m0) * KP + k0 + kq]);
            acc[0][t] = __builtin_amdgcn_mfma_f32_16x16x32_f16(a0, b, acc[0][t], 0, 0, 0);
            acc[1][t] = __builtin_amdgcn_mfma_f32_16x16x32_f16(a1, b, acc[1][t], 0, 0, 0);
        }
    }

    // C/D layout: col = lane&15, row = (lane>>4)*4 + reg (dtype-independent)
#pragma unroll
    for (int rt = 0; rt < 2; ++rt)
#pragma unroll
        for (int r = 0; r < 4; ++r) {
            int row = row0 + wave * 32 + rt * 16 + (lane >> 4) * 4 + r;
            if (row < nrows) {
                float dv = dinv[row];
#pragma unroll
                for (int t = 0; t < NT; ++t) {
                    unsigned short hv = f2h(acc[rt][t][r] * dv);
                    if (CHUNK_OUT)
                        Y[((size_t)t * NN + row) * 16 + (lane & 15)] = hv;
                    else
                        Y[(size_t)row * DOUT + t * 16 + (lane & 15)] = hv;
                }
            }
        }
}

// ---------------- aggregation D=128, chunked: XCD-affine L2-resident gather --------
// Xc: [8][N][16] fp16 slabs. chunk = blockIdx&7 -> one XCD (round-robin dispatch),
// slab = 3.2 MB < 4 MB per-XCD L2. 8 lanes per node: 4 pairs x 2 halves.
// Pair p gathers edges 4g..4g+3 for g = p, p+4, ... (4 x 16B loads in flight).
// fp16 dual-set accumulate (chain depth ~2), f32 cross-pair reduce, no LDS.
__global__ __launch_bounds__(256) void agg128_chunk(const unsigned short* __restrict__ Xc,
                                                    const int* __restrict__ csr,
                                                    const int2* __restrict__ offs2,
                                                    const float* __restrict__ dinv,
                                                    const float* __restrict__ bias,
                                                    unsigned short* __restrict__ Y, int n) {
    const int c = blockIdx.x & 7;           // chunk -> XCD via round-robin dispatch
    const int node = (blockIdx.x >> 3) * 32 + (threadIdx.x >> 3);
    if (node >= n) return;
    const int pair = (threadIdx.x >> 1) & 3;
    const int h = threadIdx.x & 1;          // features h*8 .. h*8+7 of the chunk
    const unsigned short* slab = Xc + (size_t)c * NN * 16;

    int2 se = offs2[node];
    int s = se.x, deg = se.y - se.x;
    const __half2 hz = __floats2half2_rn(0.f, 0.f);
    __half2 aA0 = hz, aA1 = hz, aA2 = hz, aA3 = hz;   // set A: edge groups 0,2
    __half2 aB0 = hz, aB1 = hz, aB2 = hz, aB3 = hz;   // set B: edge groups 1,3
    int d4 = deg >> 2;
    for (int g = pair; g < d4; g += 4) {
        const int* ip = csr + s + g * 4;
        int s0 = __builtin_nontemporal_load(ip);       // nt: don't evict the slab
        int s1 = __builtin_nontemporal_load(ip + 1);
        int s2 = __builtin_nontemporal_load(ip + 2);
        int s3 = __builtin_nontemporal_load(ip + 3);
        uint4 u0 = *(const uint4*)(slab + (size_t)s0 * 16 + h * 8);
        uint4 u1 = *(const uint4*)(slab + (size_t)s1 * 16 + h * 8);
        uint4 u2 = *(const uint4*)(slab + (size_t)s2 * 16 + h * 8);
        uint4 u3 = *(const uint4*)(slab + (size_t)s3 * 16 + h * 8);
        aA0 = __hadd2(aA0, u2h2(u0.x)); aA1 = __hadd2(aA1, u2h2(u0.y));
        aA2 = __hadd2(aA2, u2h2(u0.z)); aA3 = __hadd2(aA3, u2h2(u0.w));
        aB0 = __hadd2(aB0, u2h2(u1.x)); aB1 = __hadd2(aB1, u2h2(u1.y));
        aB2 = __hadd2(aB2, u2h2(u1.z)); aB3 = __hadd2(aB3, u2h2(u1.w));
        aA0 = __hadd2(aA0, u2h2(u2.x)); aA1 = __hadd2(aA1, u2h2(u2.y));
        aA2 = __hadd2(aA2, u2h2(u2.z)); aA3 = __hadd2(aA3, u2h2(u2.w));
        aB0 = __hadd2(aB0, u2h2(u3.x)); aB1 = __hadd2(aB1, u2h2(u3.y));
        aB2 = __hadd2(aB2, u2h2(u3.z)); aB3 = __hadd2(aB3, u2h2(u3.w));
    }
    for (int j = d4 * 4 + pair; j < deg; j += 4) {   // 0..3 tail edges
        int s0 = __builtin_nontemporal_load(csr + s + j);
        uint4 u = *(const uint4*)(slab + (size_t)s0 * 16 + h * 8);
        aA0 = __hadd2(aA0, u2h2(u.x)); aA1 = __hadd2(aA1, u2h2(u.y));
        aA2 = __hadd2(aA2, u2h2(u.z)); aA3 = __hadd2(aA3, u2h2(u.w));
    }
    if (pair == 0) {  // self-loop row (prescaled by dinv in GEMM epilogue)
        uint4 u = *(const uint4*)(slab + (size_t)node * 16 + h * 8);
        aB0 = __hadd2(aB0, u2h2(u.x)); aB1 = __hadd2(aB1, u2h2(u.y));
        aB2 = __hadd2(aB2, u2h2(u.z)); aB3 = __hadd2(aB3, u2h2(u.w));
    }
    // combine sets in f32, reduce across the 4 pairs (lane bits 1,2)
    float2 fA, fB;
    fA = __half22float2(aA0); fB = __half22float2(aB0);
    float r0 = fA.x + fB.x, r1 = fA.y + fB.y;
    fA = __half22float2(aA1); fB = __half22float2(aB1);
    float r2 = fA.x + fB.x, r3 = fA.y + fB.y;
    fA = __half22float2(aA2); fB = __half22float2(aB2);
    float r4 = fA.x + fB.x, r5 = fA.y + fB.y;
    fA = __half22float2(aA3); fB = __half22float2(aB3);
    float r6 = fA.x + fB.x, r7 = fA.y + fB.y;
    r0 += __shfl_xor(r0, 2); r0 += __shfl_xor(r0, 4);
    r1 += __shfl_xor(r1, 2); r1 += __shfl_xor(r1, 4);
    r2 += __shfl_xor(r2, 2); r2 += __shfl_xor(r2, 4);
    r3 += __shfl_xor(r3, 2); r3 += __shfl_xor(r3, 4);
    r4 += __shfl_xor(r4, 2); r4 += __shfl_xor(r4, 4);
    r5 += __shfl_xor(r5, 2); r5 += __shfl_xor(r5, 4);
    r6 += __shfl_xor(r6, 2); r6 += __shfl_xor(r6, 4);
    r7 += __shfl_xor(r7, 2); r7 += __shfl_xor(r7, 4);
    if (pair == 0) {
        float di = dinv[node];
        float4 bA = *(const float4*)(bias + c * 16 + h * 8);
        float4 bB = *(const float4*)(bias + c * 16 + h * 8 + 4);
        r0 = fmaxf(fmaf(di, r0, bA.x), 0.f); r1 = fmaxf(fmaf(di, r1, bA.y), 0.f);
        r2 = fmaxf(fmaf(di, r2, bA.z), 0.f); r3 = fmaxf(fmaf(di, r3, bA.w), 0.f);
        r4 = fmaxf(fmaf(di, r4, bB.x), 0.f); r5 = fmaxf(fmaf(di, r5, bB.y), 0.f);
        r6 = fmaxf(fmaf(di, r6, bB.z), 0.f); r7 = fmaxf(fmaf(di, r7, bB.w), 0.f);
        u32x4 o;
        o.x = h22u(__floats2half2_rn(r0, r1));
        o.y = h22u(__floats2half2_rn(r2, r3));
        o.z = h22u(__floats2half2_rn(r4, r5));
        o.w = h22u(__floats2half2_rn(r6, r7));
        // row-major output (next GEMM reads rows); nt store: keep L2 for slab
        __builtin_nontemporal_store(o, (u32x4*)(Y + (size_t)node * 128 + c * 16 + h * 8));
    }
}

// ---------------- last layer D=64: packed fp16 accumulation + log_softmax ----------------
__global__ __launch_bounds__(256) void agg_softmax64_f16(const unsigned short* __restrict__ Xp,
                                                         const int* __restrict__ csr,
                                                         const int2* __restrict__ offs2,
                                                         const float* __restrict__ dinv,
                                                         const float* __restrict__ bias,
                                                         float* __restrict__ out, int n) {
    __shared__ int sIdx[4][64];
    int wv = threadIdx.x >> 6;
    int node = blockIdx.x * 4 + wv;
    if (node >= n) return;
    int lane = threadIdx.x & 63;
    int g8 = lane >> 3;
    int l = lane & 7;
    int2 se = offs2[node];
    int s = se.x, deg = se.y - se.x;
    if (lane < deg) sIdx[wv][lane] = csr[s + lane];
    int dcap = min(deg, 64);
    const int* idx = sIdx[wv];
    const __half2 hz = __floats2half2_rn(0.f, 0.f);
    __half2 aA0 = hz, aA1 = hz, aA2 = hz, aA3 = hz;
    __half2 aB0 = hz, aB1 = hz, aB2 = hz, aB3 = hz;
    int j = g8;
    for (; j + 8 < dcap; j += 16) {
        int s0 = idx[j], s1 = idx[j + 8];
        uint4 u0 = *(const uint4*)(Xp + (size_t)s0 * 64 + l * 8);
        uint4 u1 = *(const uint4*)(Xp + (size_t)s1 * 64 + l * 8);
        aA0 = __hadd2(aA0, u2h2(u0.x)); aA1 = __hadd2(aA1, u2h2(u0.y));
        aA2 = __hadd2(aA2, u2h2(u0.z)); aA3 = __hadd2(aA3, u2h2(u0.w));
        aB0 = __hadd2(aB0, u2h2(u1.x)); aB1 = __hadd2(aB1, u2h2(u1.y));
        aB2 = __hadd2(aB2, u2h2(u1.z)); aB3 = __hadd2(aB3, u2h2(u1.w));
    }
    if (j < dcap) {
        int s0 = idx[j];
        uint4 u = *(const uint4*)(Xp + (size_t)s0 * 64 + l * 8);
        aA0 = __hadd2(aA0, u2h2(u.x)); aA1 = __hadd2(aA1, u2h2(u.y));
        aA2 = __hadd2(aA2, u2h2(u.z)); aA3 = __hadd2(aA3, u2h2(u.w));
    }
    for (int p = s + 64 + g8; p < s + deg; p += 8) {  // deg>64 safety net
        int s0 = csr[p];
        uint4 u = *(const uint4*)(Xp + (size_t)s0 * 64 + l * 8);
        aB0 = __hadd2(aB0, u2h2(u.x)); aB1 = __hadd2(aB1, u2h2(u.y));
        aB2 = __hadd2(aB2, u2h2(u.z)); aB3 = __hadd2(aB3, u2h2(u.w));
    }
    if (g8 == 0) {  // self-loop
        uint4 u = *(const uint4*)(Xp + (size_t)node * 64 + l * 8);
        aB0 = __hadd2(aB0, u2h2(u.x)); aB1 = __hadd2(aB1, u2h2(u.y));
        aB2 = __hadd2(aB2, u2h2(u.z)); aB3 = __hadd2(aB3, u2h2(u.w));
    }
    float2 fA, fB;
    fA = __half22float2(aA0); fB = __half22float2(aB0);
    float r0 = fA.x + fB.x, r1 = fA.y + fB.y;
    fA = __half22float2(aA1); fB = __half22float2(aB1);
    float r2 = fA.x + fB.x, r3 = fA.y + fB.y;
    fA = __half22float2(aA2); fB = __half22float2(aB2);
    float r4 = fA.x + fB.x, r5 = fA.y + fB.y;
    fA = __half22float2(aA3); fB = __half22float2(aB3);
    float r6 = fA.x + fB.x, r7 = fA.y + fB.y;
    r0 += __shfl_xor(r0, 8); r0 += __shfl_xor(r0, 16); r0 += __shfl_xor(r0, 32);
    r1 += __shfl_xor(r1, 8); r1 += __shfl_xor(r1, 16); r1 += __shfl_xor(r1, 32);
    r2 += __shfl_xor(r2, 8); r2 += __shfl_xor(r2, 16); r2 += __shfl_xor(r2, 32);
    r3 += __shfl_xor(r3, 8); r3 += __shfl_xor(r3, 16); r3 += __shfl_xor(r3, 32);
    r4 += __shfl_xor(r4, 8); r4 += __shfl_xor(r4, 16); r4 += __shfl_xor(r4, 32);
    r5 += __shfl_xor(r5, 8); r5 += __shfl_xor(r5, 16); r5 += __shfl_xor(r5, 32);
    r6 += __shfl_xor(r6, 8); r6 += __shfl_xor(r6, 16); r6 += __shfl_xor(r6, 32);
    r7 += __shfl_xor(r7, 8); r7 += __shfl_xor(r7, 16); r7 += __shfl_xor(r7, 32);
    if (g8 == 0) {
        float di = dinv[node];
        float4 bA = *(const float4*)(bias + l * 8);
        float4 bB = *(const float4*)(bias + l * 8 + 4);
        r0 = fmaf(di, r0, bA.x); r1 = fmaf(di, r1, bA.y);
        r2 = fmaf(di, r2, bA.z); r3 = fmaf(di, r3, bA.w);
        r4 = fmaf(di, r4, bB.x); r5 = fmaf(di, r5, bB.y);
        r6 = fmaf(di, r6, bB.z); r7 = fmaf(di, r7, bB.w);
        float m = fmaxf(fmaxf(fmaxf(r0, r1), fmaxf(r2, r3)), fmaxf(fmaxf(r4, r5), fmaxf(r6, r7)));
#pragma unroll
        for (int o = 4; o > 0; o >>= 1) m = fmaxf(m, __shfl_xor(m, o));
        float ssum = __expf(r0 - m) + __expf(r1 - m) + __expf(r2 - m) + __expf(r3 - m) +
                     __expf(r4 - m) + __expf(r5 - m) + __expf(r6 - m) + __expf(r7 - m);
#pragma unroll
        for (int o = 4; o > 0; o >>= 1) ssum += __shfl_xor(ssum, o);
        float lg = m + __logf(ssum);
        float4 o0 = make_float4(r0 - lg, r1 - lg, r2 - lg, r3 - lg);
        float4 o1 = make_float4(r4 - lg, r5 - lg, r6 - lg, r7 - lg);
        *(float4*)(out + (size_t)node * 64 + l * 8) = o0;
        *(float4*)(out + (size_t)node * 64 + l * 8 + 4) = o1;
    }
}

// ---------------- launcher ----------------

extern "C" void kernel_launch(void* const* d_in, const int* in_sizes, int n_in,
                              void* d_out, int out_size, void* d_ws, size_t ws_size,
                              hipStream_t stream) {
    const int* edges = (const int*)d_in[0];
    const float* feat = (const float*)d_in[1];
    const float* W0 = (const float*)d_in[2];
    const float* b0 = (const float*)d_in[3];
    const float* W1 = (const float*)d_in[4];
    const float* b1 = (const float*)d_in[5];
    const float* W2 = (const float*)d_in[6];
    const float* b2 = (const float*)d_in[7];

    const int N = NN;
    const int E = EE;

    char* ws = (char*)d_ws;
    int* bcount = (int*)ws;                       // NB2
    int2* offs2 = (int2*)(bcount + ((NB2 + 1) & ~1));  // N (8B aligned)
    float* dinv = (float*)(offs2 + N);            // N
    int* P = (int*)(dinv + N);                    // NB2*CAP (packed src<<7|dst&127)
    int* csr = P + (size_t)NB2 * CAP;             // NB2*CAP (src only)
    unsigned short* Wt0 = (unsigned short*)(csr + (size_t)NB2 * CAP);  // 16384
    unsigned short* Wt1 = Wt0 + 16384;            // 16384
    unsigned short* Wt2 = Wt1 + 16384;            // 8192
    size_t off = (size_t)((char*)(Wt2 + 8192) - ws);
    off = (off + 255) & ~(size_t)255;
    unsigned short* bufA = (unsigned short*)(ws + off);  // N*128 fp16
    unsigned short* bufB = bufA + (size_t)N * 128;       // N*128 fp16

    const int* esrc = edges;
    const int* edst = edges + E;

    // CSR build
    prep_weights<<<160, 256, 0, stream>>>(W0, W1, W2, Wt0, Wt1, Wt2, bcount);
    scatter_bump<<<NPART, 256, 0, stream>>>(esrc, edst, bcount, P, E);
    bucket_build<<<NB2, 256, 0, stream>>>(P, bcount, offs2, dinv, csr, N);

    const int gemmBlocks = (N + 127) / 128;       // 782
    const int aggChunkBlocks = 8 * ((N + 31) / 32);  // 25000 (chunk x node-group)
    const int aggBlocks = (N + 3) / 4;            // 25000

    // layer 0 (GEMM writes chunk-major slabs; agg is XCD-affine per chunk)
    gemm_mfma<128, true, true><<<gemmBlocks, 256, 0, stream>>>(feat, Wt0, dinv, bufA, N);
    agg128_chunk<<<aggChunkBlocks, 256, 0, stream>>>(bufA, csr, offs2, dinv, b0, bufB, N);
    // layer 1
    gemm_mfma<128, false, true><<<gemmBlocks, 256, 0, stream>>>(bufB, Wt1, dinv, bufA, N);
    agg128_chunk<<<aggChunkBlocks, 256, 0, stream>>>(bufA, csr, offs2, dinv, b1, bufB, N);
    // layer 2 + log_softmax (row-major output, unchanged softmax kernel)
    gemm_mfma<64, false, false><<<gemmBlocks, 256, 0, stream>>>(bufB, Wt2, dinv, bufA, N);
    agg_softmax64_f16<<<aggBlocks, 256, 0, stream>>>(bufA, csr, offs2, dinv, b2, (float*)d_out, N);
}

// Round 3
// 453.440 us; speedup vs baseline: 1.1707x; 1.1707x over previous
//
#include <hip/hip_runtime.h>
#include <hip/hip_fp16.h>
#include <math.h>

// StackedGCN: N=100000, E=1600000, 128 -> 128 -> 128 -> 64, fp32 in/out.
// FP16 activation pipeline, fp32 MFMA accumulation, dinv prescaled in GEMM
// epilogue.
// Round-3 A/B experiment (both agg variants in one run, profiled separately):
//   layer-0 agg: row-major 256B-row gather (baseline structure) with
//     NONTEMPORAL gather loads -> tests whether L1 allocation/fill rate is
//     the ~107 G-granule/s cap.
//   layer-1 agg: 32-feature x 4-chunk slabs (64B rows = 1 granule/edge,
//     same granule count as row-major) with 2-XCD affinity (chunk c ->
//     XCDs {c, c+4} under round-robin blockIdx%8) -> tests whether
//     L2-resident granules are served meaningfully faster.
#define NN 100000
#define EE 1600000
#define NB2 782     // dst buckets: dst>>7 -> 128 nodes per bucket
#define BN 128      // nodes per bucket
#define NPART 512   // scatter_bump blocks
#define CAP 2560    // padded segment capacity (mean 2048, sd ~45 -> +11 sigma)

typedef __attribute__((ext_vector_type(8))) _Float16 half8;
typedef __attribute__((ext_vector_type(4))) float f32x4;
typedef __attribute__((ext_vector_type(4))) unsigned int u32x4;

__device__ inline unsigned short f2h(float x) {
    return __half_as_ushort(__float2half(x));
}
__device__ inline __half2 u2h2(unsigned u) {
    return __builtin_bit_cast(__half2, u);
}
__device__ inline unsigned h22u(__half2 h) {
    return __builtin_bit_cast(unsigned, h);
}
template <bool NT>
__device__ inline u32x4 ld16(const unsigned short* p) {
    if (NT) return __builtin_nontemporal_load((const u32x4*)p);
    return *(const u32x4*)p;
}

// ---------------- weight prep (+ bcount zero) ----------------

__global__ void prep_weights(const float* __restrict__ W0, const float* __restrict__ W1,
                             const float* __restrict__ W2, unsigned short* __restrict__ Wt0,
                             unsigned short* __restrict__ Wt1, unsigned short* __restrict__ Wt2,
                             int* __restrict__ bcount) {
    int g = blockIdx.x * 256 + threadIdx.x;
    if (g < NB2) bcount[g] = 0;
    if (g < 16384) {
        int n = g >> 7, k = g & 127;
        Wt0[g] = f2h(W0[k * 128 + n]);
    } else if (g < 32768) {
        int i = g - 16384;
        int n = i >> 7, k = i & 127;
        Wt1[i] = f2h(W1[k * 128 + n]);
    } else if (g < 40960) {
        int i = g - 32768;
        int n = i >> 7, k = i & 127;
        Wt2[i] = f2h(W2[k * 64 + n]);
    }
}

// ---------------- CSR build ----------------

__global__ __launch_bounds__(256) void scatter_bump(const int* __restrict__ src,
                                                    const int* __restrict__ dst,
                                                    int* __restrict__ bcount,
                                                    int* __restrict__ P, int e) {
    __shared__ int cnt[NB2];
    __shared__ int basep[NB2];
    __shared__ int cur[NB2];
    int t = threadIdx.x;
    for (int i = t; i < NB2; i += 256) { cnt[i] = 0; cur[i] = 0; }
    __syncthreads();
    int chunk = (e + NPART - 1) / NPART;
    int b0 = blockIdx.x * chunk, b1 = min(e, b0 + chunk);
    for (int i = b0 + t; i < b1; i += 256)
        atomicAdd(&cnt[dst[i] >> 7], 1);
    __syncthreads();
    for (int i = t; i < NB2; i += 256) {
        int c = cnt[i];
        basep[i] = c ? atomicAdd(&bcount[i], c) : 0;
    }
    __syncthreads();
    for (int i = b0 + t; i < b1; i += 256) {  // second read is L2-hot
        int d = dst[i];
        int b = d >> 7;
        int p = basep[b] + atomicAdd(&cur[b], 1);
        P[(size_t)b * CAP + p] = (src[i] << 7) | (d & 127);  // src<2^17: 24 bits
    }
}

__global__ __launch_bounds__(256) void bucket_build(const int* __restrict__ P,
                                                    const int* __restrict__ bcount,
                                                    int2* __restrict__ offs2,
                                                    float* __restrict__ dinv,
                                                    int* __restrict__ csr, int n) {
    __shared__ int cnt[BN];
    __shared__ int sc[BN];
    __shared__ int cur[BN];
    __shared__ int stage[CAP];
    int b = blockIdx.x, t = threadIdx.x;
    int base = b * CAP;
    int count = bcount[b];
    if (t < BN) cnt[t] = 0;
    __syncthreads();
    for (int i = t; i < count; i += 256)
        atomicAdd(&cnt[P[base + i] & 127], 1);
    __syncthreads();
    int v = 0;
    if (t < BN) {
        v = cnt[t];
        sc[t] = v;
    }
    for (int d = 1; d < BN; d <<= 1) {
        __syncthreads();
        int x = (t < BN && t >= d) ? sc[t - d] : 0;
        __syncthreads();
        if (t < BN) sc[t] += x;
    }
    __syncthreads();
    if (t < BN) {
        int myoff = sc[t] - v;
        int node = b * BN + t;
        if (node < n) {
            offs2[node] = make_int2(base + myoff, base + myoff + v);
            dinv[node] = 1.0f / sqrtf((float)(v + 1));  // +1 self-loop
        }
        cur[t] = myoff;
    }
    __syncthreads();
    for (int i = t; i < count; i += 256) {  // second read L2-hot
        int pe = P[base + i];
        int p = atomicAdd(&cur[pe & 127], 1);
        stage[p] = ((unsigned)pe) >> 7;     // p < count <= CAP always
    }
    __syncthreads();
    for (int i = t; i < count; i += 256) csr[base + i] = stage[i];
}

// ---------------- MFMA GEMM (f16) + dinv-prescale epilogue ----------------
// OMODE 0: row-major Y[row][DOUT]
// OMODE 1: 32-feature chunk slabs Xc[t>>1][row][32] (chunk = pair of 16-col tiles)
template <int DOUT, bool A_IS_F32, int OMODE>
__global__ __launch_bounds__(256) void gemm_mfma(const void* __restrict__ Aptr,
                                                 const unsigned short* __restrict__ Wt,
                                                 const float* __restrict__ dinv,
                                                 unsigned short* __restrict__ Y, int nrows) {
    constexpr int KP = 136;
    constexpr int NT = DOUT / 16;
    __shared__ unsigned short sA[128 * KP];
    __shared__ unsigned short sB[DOUT * KP];
    const int row0 = blockIdx.x * 128;
    const int tid = threadIdx.x;

    for (int i = tid; i < DOUT * 16; i += 256) {
        int n = i >> 4, c = (i & 15) * 8;
        uint4 v = *(const uint4*)(Wt + n * 128 + c);
        *(uint4*)(&sB[n * KP + c]) = v;
    }
    if (A_IS_F32) {
        const float* A = (const float*)Aptr;
        for (int i = tid; i < 128 * 32; i += 256) {
            int r = i >> 5, c = (i & 31) * 4;
            float4 v = make_float4(0.f, 0.f, 0.f, 0.f);
            if (row0 + r < nrows) v = *(const float4*)(A + (size_t)(row0 + r) * 128 + c);
            uint2 o;
            o.x = h22u(__floats2half2_rn(v.x, v.y));
            o.y = h22u(__floats2half2_rn(v.z, v.w));
            *(uint2*)(&sA[r * KP + c]) = o;
        }
    } else {
        const unsigned short* A = (const unsigned short*)Aptr;
        for (int i = tid; i < 128 * 16; i += 256) {
            int r = i >> 4, c = (i & 15) * 8;
            uint4 v = make_uint4(0u, 0u, 0u, 0u);
            if (row0 + r < nrows) v = *(const uint4*)(A + (size_t)(row0 + r) * 128 + c);
            *(uint4*)(&sA[r * KP + c]) = v;
        }
    }
    __syncthreads();

    const int wave = tid >> 6;
    const int lane = tid & 63;
    const int m0 = lane & 15;
    const int kq = (lane >> 4) * 8;

    f32x4 acc[2][NT];
#pragma unroll
    for (int rt = 0; rt < 2; ++rt)
#pragma unroll
        for (int t = 0; t < NT; ++t) acc[rt][t] = (f32x4){0.f, 0.f, 0.f, 0.f};

#pragma unroll
    for (int k0 = 0; k0 < 128; k0 += 32) {
        half8 a0 = *(const half8*)(&sA[(wave * 32 + m0) * KP + k0 + kq]);
        half8 a1 = *(const half8*)(&sA[(wave * 32 + 16 + m0) * KP + k0 + kq]);
#pragma unroll
        for (int t = 0; t < NT; ++t) {
            half8 b = *(const half8*)(&sB[(t * 16 + m0) * KP + k0 + kq]);
            acc[0][t] = __builtin_amdgcn_mfma_f32_16x16x32_f16(a0, b, acc[0][t], 0, 0, 0);
            acc[1][t] = __builtin_amdgcn_mfma_f32_16x16x32_f16(a1, b, acc[1][t], 0, 0, 0);
        }
    }

    // C/D layout: col = lane&15, row = (lane>>4)*4 + reg (dtype-independent)
#pragma unroll
    for (int rt = 0; rt < 2; ++rt)
#pragma unroll
        for (int r = 0; r < 4; ++r) {
            int row = row0 + wave * 32 + rt * 16 + (lane >> 4) * 4 + r;
            if (row < nrows) {
                float dv = dinv[row];
#pragma unroll
                for (int t = 0; t < NT; ++t) {
                    unsigned short hv = f2h(acc[rt][t][r] * dv);
                    if (OMODE == 1)
                        Y[(((size_t)(t >> 1) * NN + row) << 5) + ((t & 1) << 4) + (lane & 15)] = hv;
                    else
                        Y[(size_t)row * DOUT + t * 16 + (lane & 15)] = hv;
                }
            }
        }
}

// ---------------- aggregation D=128 row-major: LDS-staged list, packed fp16 acc --------
// NTG: nontemporal gather loads (bypass/evict-first hint on L1) - A/B probe.
template <bool NTG>
__global__ __launch_bounds__(256) void agg128_f16(const unsigned short* __restrict__ Xp,
                                                  const int* __restrict__ csr,
                                                  const int2* __restrict__ offs2,
                                                  const float* __restrict__ dinv,
                                                  const float* __restrict__ bias,
                                                  unsigned short* __restrict__ Y, int n) {
    __shared__ int sIdx[4][64];
    int wv = threadIdx.x >> 6;
    int node = blockIdx.x * 4 + wv;
    if (node >= n) return;
    int lane = threadIdx.x & 63;
    int q = lane >> 4;
    int l = lane & 15;
    int2 se = offs2[node];
    int s = se.x, deg = se.y - se.x;
    if (lane < deg) sIdx[wv][lane] = csr[s + lane];
    int dcap = min(deg, 64);
    const int* idx = sIdx[wv];   // same-wave LDS: program-ordered, no barrier
    const __half2 hz = __floats2half2_rn(0.f, 0.f);
    __half2 aA0 = hz, aA1 = hz, aA2 = hz, aA3 = hz;   // set A: edges j, j+8
    __half2 aB0 = hz, aB1 = hz, aB2 = hz, aB3 = hz;   // set B: edges j+4, j+12
    int j = q;
    for (; j + 12 < dcap; j += 16) {  // 4 gathers in flight per quarter-wave
        int s0 = idx[j], s1 = idx[j + 4], s2 = idx[j + 8], s3 = idx[j + 12];
        u32x4 u0 = ld16<NTG>(Xp + (size_t)s0 * 128 + l * 8);
        u32x4 u1 = ld16<NTG>(Xp + (size_t)s1 * 128 + l * 8);
        u32x4 u2 = ld16<NTG>(Xp + (size_t)s2 * 128 + l * 8);
        u32x4 u3 = ld16<NTG>(Xp + (size_t)s3 * 128 + l * 8);
        aA0 = __hadd2(aA0, u2h2(u0.x)); aA1 = __hadd2(aA1, u2h2(u0.y));
        aA2 = __hadd2(aA2, u2h2(u0.z)); aA3 = __hadd2(aA3, u2h2(u0.w));
        aB0 = __hadd2(aB0, u2h2(u1.x)); aB1 = __hadd2(aB1, u2h2(u1.y));
        aB2 = __hadd2(aB2, u2h2(u1.z)); aB3 = __hadd2(aB3, u2h2(u1.w));
        aA0 = __hadd2(aA0, u2h2(u2.x)); aA1 = __hadd2(aA1, u2h2(u2.y));
        aA2 = __hadd2(aA2, u2h2(u2.z)); aA3 = __hadd2(aA3, u2h2(u2.w));
        aB0 = __hadd2(aB0, u2h2(u3.x)); aB1 = __hadd2(aB1, u2h2(u3.y));
        aB2 = __hadd2(aB2, u2h2(u3.z)); aB3 = __hadd2(aB3, u2h2(u3.w));
    }
    for (; j < dcap; j += 4) {
        int s0 = idx[j];
        u32x4 u = ld16<NTG>(Xp + (size_t)s0 * 128 + l * 8);
        aA0 = __hadd2(aA0, u2h2(u.x)); aA1 = __hadd2(aA1, u2h2(u.y));
        aA2 = __hadd2(aA2, u2h2(u.z)); aA3 = __hadd2(aA3, u2h2(u.w));
    }
    for (int p = s + 64 + q; p < s + deg; p += 4) {  // deg>64 safety net
        int s0 = csr[p];
        u32x4 u = ld16<NTG>(Xp + (size_t)s0 * 128 + l * 8);
        aB0 = __hadd2(aB0, u2h2(u.x)); aB1 = __hadd2(aB1, u2h2(u.y));
        aB2 = __hadd2(aB2, u2h2(u.z)); aB3 = __hadd2(aB3, u2h2(u.w));
    }
    if (q == 0) {  // self-loop row (prescaled)
        u32x4 u = ld16<NTG>(Xp + (size_t)node * 128 + l * 8);
        aB0 = __hadd2(aB0, u2h2(u.x)); aB1 = __hadd2(aB1, u2h2(u.y));
        aB2 = __hadd2(aB2, u2h2(u.z)); aB3 = __hadd2(aB3, u2h2(u.w));
    }
    // combine sets in f32, then cross-lane reduce in f32
    float2 fA, fB;
    fA = __half22float2(aA0); fB = __half22float2(aB0);
    float r0 = fA.x + fB.x, r1 = fA.y + fB.y;
    fA = __half22float2(aA1); fB = __half22float2(aB1);
    float r2 = fA.x + fB.x, r3 = fA.y + fB.y;
    fA = __half22float2(aA2); fB = __half22float2(aB2);
    float r4 = fA.x + fB.x, r5 = fA.y + fB.y;
    fA = __half22float2(aA3); fB = __half22float2(aB3);
    float r6 = fA.x + fB.x, r7 = fA.y + fB.y;
    r0 += __shfl_xor(r0, 16); r0 += __shfl_xor(r0, 32);
    r1 += __shfl_xor(r1, 16); r1 += __shfl_xor(r1, 32);
    r2 += __shfl_xor(r2, 16); r2 += __shfl_xor(r2, 32);
    r3 += __shfl_xor(r3, 16); r3 += __shfl_xor(r3, 32);
    r4 += __shfl_xor(r4, 16); r4 += __shfl_xor(r4, 32);
    r5 += __shfl_xor(r5, 16); r5 += __shfl_xor(r5, 32);
    r6 += __shfl_xor(r6, 16); r6 += __shfl_xor(r6, 32);
    r7 += __shfl_xor(r7, 16); r7 += __shfl_xor(r7, 32);
    if (q == 0) {
        float di = dinv[node];
        float4 bA = *(const float4*)(bias + l * 8);
        float4 bB = *(const float4*)(bias + l * 8 + 4);
        r0 = fmaxf(fmaf(di, r0, bA.x), 0.f); r1 = fmaxf(fmaf(di, r1, bA.y), 0.f);
        r2 = fmaxf(fmaf(di, r2, bA.z), 0.f); r3 = fmaxf(fmaf(di, r3, bA.w), 0.f);
        r4 = fmaxf(fmaf(di, r4, bB.x), 0.f); r5 = fmaxf(fmaf(di, r5, bB.y), 0.f);
        r6 = fmaxf(fmaf(di, r6, bB.z), 0.f); r7 = fmaxf(fmaf(di, r7, bB.w), 0.f);
        uint4 o;
        o.x = h22u(__floats2half2_rn(r0, r1));
        o.y = h22u(__floats2half2_rn(r2, r3));
        o.z = h22u(__floats2half2_rn(r4, r5));
        o.w = h22u(__floats2half2_rn(r6, r7));
        *(uint4*)(Y + (size_t)node * 128 + l * 8) = o;
    }
}

// ---------------- aggregation D=128, 32-feature chunks: 2-XCD-affine gather --------
// Xc: [4][N][32] fp16 slabs (64B rows = 1 granule/edge). chunk = blockIdx&3 ->
// XCDs {c, c+4} under round-robin. 16 lanes/node: 4 quads x 4 features-of-8.
// Quad p gathers 4 consecutive edges per iter (4 x 16B loads in flight; the 4
// csr dwords per quad x 4 quads = one 64B csr line per node per iter).
__global__ __launch_bounds__(256) void agg128_c32(const unsigned short* __restrict__ Xc,
                                                  const int* __restrict__ csr,
                                                  const int2* __restrict__ offs2,
                                                  const float* __restrict__ dinv,
                                                  const float* __restrict__ bias,
                                                  unsigned short* __restrict__ Y, int n) {
    const int c = blockIdx.x & 3;
    const int node = (blockIdx.x >> 2) * 16 + (threadIdx.x >> 4);
    if (node >= n) return;
    const int p = (threadIdx.x >> 2) & 3;
    const int h = threadIdx.x & 3;          // features h*8 .. h*8+7 of the chunk
    const unsigned short* slab = Xc + (size_t)c * NN * 32;

    int2 se = offs2[node];
    int s = se.x, deg = se.y - se.x;
    const __half2 hz = __floats2half2_rn(0.f, 0.f);
    __half2 aA0 = hz, aA1 = hz, aA2 = hz, aA3 = hz;
    __half2 aB0 = hz, aB1 = hz, aB2 = hz, aB3 = hz;
    int d4 = deg >> 2;
    for (int g = p; g < d4; g += 4) {
        const int* ip = csr + s + g * 4;
        int s0 = __builtin_nontemporal_load(ip);   // nt: stream, don't evict slab
        int s1 = __builtin_nontemporal_load(ip + 1);
        int s2 = __builtin_nontemporal_load(ip + 2);
        int s3 = __builtin_nontemporal_load(ip + 3);
        u32x4 u0 = *(const u32x4*)(slab + (size_t)s0 * 32 + h * 8);
        u32x4 u1 = *(const u32x4*)(slab + (size_t)s1 * 32 + h * 8);
        u32x4 u2 = *(const u32x4*)(slab + (size_t)s2 * 32 + h * 8);
        u32x4 u3 = *(const u32x4*)(slab + (size_t)s3 * 32 + h * 8);
        aA0 = __hadd2(aA0, u2h2(u0.x)); aA1 = __hadd2(aA1, u2h2(u0.y));
        aA2 = __hadd2(aA2, u2h2(u0.z)); aA3 = __hadd2(aA3, u2h2(u0.w));
        aB0 = __hadd2(aB0, u2h2(u1.x)); aB1 = __hadd2(aB1, u2h2(u1.y));
        aB2 = __hadd2(aB2, u2h2(u1.z)); aB3 = __hadd2(aB3, u2h2(u1.w));
        aA0 = __hadd2(aA0, u2h2(u2.x)); aA1 = __hadd2(aA1, u2h2(u2.y));
        aA2 = __hadd2(aA2, u2h2(u2.z)); aA3 = __hadd2(aA3, u2h2(u2.w));
        aB0 = __hadd2(aB0, u2h2(u3.x)); aB1 = __hadd2(aB1, u2h2(u3.y));
        aB2 = __hadd2(aB2, u2h2(u3.z)); aB3 = __hadd2(aB3, u2h2(u3.w));
    }
    for (int j = d4 * 4 + p; j < deg; j += 4) {   // 0..3 tail edges
        int s0 = __builtin_nontemporal_load(csr + s + j);
        u32x4 u = *(const u32x4*)(slab + (size_t)s0 * 32 + h * 8);
        aA0 = __hadd2(aA0, u2h2(u.x)); aA1 = __hadd2(aA1, u2h2(u.y));
        aA2 = __hadd2(aA2, u2h2(u.z)); aA3 = __hadd2(aA3, u2h2(u.w));
    }
    if (p == 0) {  // self-loop row (prescaled by dinv in GEMM epilogue)
        u32x4 u = *(const u32x4*)(slab + (size_t)node * 32 + h * 8);
        aB0 = __hadd2(aB0, u2h2(u.x)); aB1 = __hadd2(aB1, u2h2(u.y));
        aB2 = __hadd2(aB2, u2h2(u.z)); aB3 = __hadd2(aB3, u2h2(u.w));
    }
    // combine sets in f32, reduce across the 4 quads (lane bits 2,3)
    float2 fA, fB;
    fA = __half22float2(aA0); fB = __half22float2(aB0);
    float r0 = fA.x + fB.x, r1 = fA.y + fB.y;
    fA = __half22float2(aA1); fB = __half22float2(aB1);
    float r2 = fA.x + fB.x, r3 = fA.y + fB.y;
    fA = __half22float2(aA2); fB = __half22float2(aB2);
    float r4 = fA.x + fB.x, r5 = fA.y + fB.y;
    fA = __half22float2(aA3); fB = __half22float2(aB3);
    float r6 = fA.x + fB.x, r7 = fA.y + fB.y;
    r0 += __shfl_xor(r0, 4); r0 += __shfl_xor(r0, 8);
    r1 += __shfl_xor(r1, 4); r1 += __shfl_xor(r1, 8);
    r2 += __shfl_xor(r2, 4); r2 += __shfl_xor(r2, 8);
    r3 += __shfl_xor(r3, 4); r3 += __shfl_xor(r3, 8);
    r4 += __shfl_xor(r4, 4); r4 += __shfl_xor(r4, 8);
    r5 += __shfl_xor(r5, 4); r5 += __shfl_xor(r5, 8);
    r6 += __shfl_xor(r6, 4); r6 += __shfl_xor(r6, 8);
    r7 += __shfl_xor(r7, 4); r7 += __shfl_xor(r7, 8);
    if (p == 0) {
        float di = dinv[node];
        float4 bA = *(const float4*)(bias + c * 32 + h * 8);
        float4 bB = *(const float4*)(bias + c * 32 + h * 8 + 4);
        r0 = fmaxf(fmaf(di, r0, bA.x), 0.f); r1 = fmaxf(fmaf(di, r1, bA.y), 0.f);
        r2 = fmaxf(fmaf(di, r2, bA.z), 0.f); r3 = fmaxf(fmaf(di, r3, bA.w), 0.f);
        r4 = fmaxf(fmaf(di, r4, bB.x), 0.f); r5 = fmaxf(fmaf(di, r5, bB.y), 0.f);
        r6 = fmaxf(fmaf(di, r6, bB.z), 0.f); r7 = fmaxf(fmaf(di, r7, bB.w), 0.f);
        u32x4 o;
        o.x = h22u(__floats2half2_rn(r0, r1));
        o.y = h22u(__floats2half2_rn(r2, r3));
        o.z = h22u(__floats2half2_rn(r4, r5));
        o.w = h22u(__floats2half2_rn(r6, r7));
        // row-major output; 4 h-lanes -> 64B contiguous per node
        *(u32x4*)(Y + (size_t)node * 128 + c * 32 + h * 8) = o;
    }
}

// ---------------- last layer D=64: packed fp16 accumulation + log_softmax ----------------
__global__ __launch_bounds__(256) void agg_softmax64_f16(const unsigned short* __restrict__ Xp,
                                                         const int* __restrict__ csr,
                                                         const int2* __restrict__ offs2,
                                                         const float* __restrict__ dinv,
                                                         const float* __restrict__ bias,
                                                         float* __restrict__ out, int n) {
    __shared__ int sIdx[4][64];
    int wv = threadIdx.x >> 6;
    int node = blockIdx.x * 4 + wv;
    if (node >= n) return;
    int lane = threadIdx.x & 63;
    int g8 = lane >> 3;
    int l = lane & 7;
    int2 se = offs2[node];
    int s = se.x, deg = se.y - se.x;
    if (lane < deg) sIdx[wv][lane] = csr[s + lane];
    int dcap = min(deg, 64);
    const int* idx = sIdx[wv];
    const __half2 hz = __floats2half2_rn(0.f, 0.f);
    __half2 aA0 = hz, aA1 = hz, aA2 = hz, aA3 = hz;
    __half2 aB0 = hz, aB1 = hz, aB2 = hz, aB3 = hz;
    int j = g8;
    for (; j + 8 < dcap; j += 16) {
        int s0 = idx[j], s1 = idx[j + 8];
        uint4 u0 = *(const uint4*)(Xp + (size_t)s0 * 64 + l * 8);
        uint4 u1 = *(const uint4*)(Xp + (size_t)s1 * 64 + l * 8);
        aA0 = __hadd2(aA0, u2h2(u0.x)); aA1 = __hadd2(aA1, u2h2(u0.y));
        aA2 = __hadd2(aA2, u2h2(u0.z)); aA3 = __hadd2(aA3, u2h2(u0.w));
        aB0 = __hadd2(aB0, u2h2(u1.x)); aB1 = __hadd2(aB1, u2h2(u1.y));
        aB2 = __hadd2(aB2, u2h2(u1.z)); aB3 = __hadd2(aB3, u2h2(u1.w));
    }
    if (j < dcap) {
        int s0 = idx[j];
        uint4 u = *(const uint4*)(Xp + (size_t)s0 * 64 + l * 8);
        aA0 = __hadd2(aA0, u2h2(u.x)); aA1 = __hadd2(aA1, u2h2(u.y));
        aA2 = __hadd2(aA2, u2h2(u.z)); aA3 = __hadd2(aA3, u2h2(u.w));
    }
    for (int p = s + 64 + g8; p < s + deg; p += 8) {  // deg>64 safety net
        int s0 = csr[p];
        uint4 u = *(const uint4*)(Xp + (size_t)s0 * 64 + l * 8);
        aB0 = __hadd2(aB0, u2h2(u.x)); aB1 = __hadd2(aB1, u2h2(u.y));
        aB2 = __hadd2(aB2, u2h2(u.z)); aB3 = __hadd2(aB3, u2h2(u.w));
    }
    if (g8 == 0) {  // self-loop
        uint4 u = *(const uint4*)(Xp + (size_t)node * 64 + l * 8);
        aB0 = __hadd2(aB0, u2h2(u.x)); aB1 = __hadd2(aB1, u2h2(u.y));
        aB2 = __hadd2(aB2, u2h2(u.z)); aB3 = __hadd2(aB3, u2h2(u.w));
    }
    float2 fA, fB;
    fA = __half22float2(aA0); fB = __half22float2(aB0);
    float r0 = fA.x + fB.x, r1 = fA.y + fB.y;
    fA = __half22float2(aA1); fB = __half22float2(aB1);
    float r2 = fA.x + fB.x, r3 = fA.y + fB.y;
    fA = __half22float2(aA2); fB = __half22float2(aB2);
    float r4 = fA.x + fB.x, r5 = fA.y + fB.y;
    fA = __half22float2(aA3); fB = __half22float2(aB3);
    float r6 = fA.x + fB.x, r7 = fA.y + fB.y;
    r0 += __shfl_xor(r0, 8); r0 += __shfl_xor(r0, 16); r0 += __shfl_xor(r0, 32);
    r1 += __shfl_xor(r1, 8); r1 += __shfl_xor(r1, 16); r1 += __shfl_xor(r1, 32);
    r2 += __shfl_xor(r2, 8); r2 += __shfl_xor(r2, 16); r2 += __shfl_xor(r2, 32);
    r3 += __shfl_xor(r3, 8); r3 += __shfl_xor(r3, 16); r3 += __shfl_xor(r3, 32);
    r4 += __shfl_xor(r4, 8); r4 += __shfl_xor(r4, 16); r4 += __shfl_xor(r4, 32);
    r5 += __shfl_xor(r5, 8); r5 += __shfl_xor(r5, 16); r5 += __shfl_xor(r5, 32);
    r6 += __shfl_xor(r6, 8); r6 += __shfl_xor(r6, 16); r6 += __shfl_xor(r6, 32);
    r7 += __shfl_xor(r7, 8); r7 += __shfl_xor(r7, 16); r7 += __shfl_xor(r7, 32);
    if (g8 == 0) {
        float di = dinv[node];
        float4 bA = *(const float4*)(bias + l * 8);
        float4 bB = *(const float4*)(bias + l * 8 + 4);
        r0 = fmaf(di, r0, bA.x); r1 = fmaf(di, r1, bA.y);
        r2 = fmaf(di, r2, bA.z); r3 = fmaf(di, r3, bA.w);
        r4 = fmaf(di, r4, bB.x); r5 = fmaf(di, r5, bB.y);
        r6 = fmaf(di, r6, bB.z); r7 = fmaf(di, r7, bB.w);
        float m = fmaxf(fmaxf(fmaxf(r0, r1), fmaxf(r2, r3)), fmaxf(fmaxf(r4, r5), fmaxf(r6, r7)));
#pragma unroll
        for (int o = 4; o > 0; o >>= 1) m = fmaxf(m, __shfl_xor(m, o));
        float ssum = __expf(r0 - m) + __expf(r1 - m) + __expf(r2 - m) + __expf(r3 - m) +
                     __expf(r4 - m) + __expf(r5 - m) + __expf(r6 - m) + __expf(r7 - m);
#pragma unroll
        for (int o = 4; o > 0; o >>= 1) ssum += __shfl_xor(ssum, o);
        float lg = m + __logf(ssum);
        float4 o0 = make_float4(r0 - lg, r1 - lg, r2 - lg, r3 - lg);
        float4 o1 = make_float4(r4 - lg, r5 - lg, r6 - lg, r7 - lg);
        *(float4*)(out + (size_t)node * 64 + l * 8) = o0;
        *(float4*)(out + (size_t)node * 64 + l * 8 + 4) = o1;
    }
}

// ---------------- launcher ----------------

extern "C" void kernel_launch(void* const* d_in, const int* in_sizes, int n_in,
                              void* d_out, int out_size, void* d_ws, size_t ws_size,
                              hipStream_t stream) {
    const int* edges = (const int*)d_in[0];
    const float* feat = (const float*)d_in[1];
    const float* W0 = (const float*)d_in[2];
    const float* b0 = (const float*)d_in[3];
    const float* W1 = (const float*)d_in[4];
    const float* b1 = (const float*)d_in[5];
    const float* W2 = (const float*)d_in[6];
    const float* b2 = (const float*)d_in[7];

    const int N = NN;
    const int E = EE;

    char* ws = (char*)d_ws;
    int* bcount = (int*)ws;                       // NB2
    int2* offs2 = (int2*)(bcount + ((NB2 + 1) & ~1));  // N (8B aligned)
    float* dinv = (float*)(offs2 + N);            // N
    int* P = (int*)(dinv + N);                    // NB2*CAP (packed src<<7|dst&127)
    int* csr = P + (size_t)NB2 * CAP;             // NB2*CAP (src only)
    unsigned short* Wt0 = (unsigned short*)(csr + (size_t)NB2 * CAP);  // 16384
    unsigned short* Wt1 = Wt0 + 16384;            // 16384
    unsigned short* Wt2 = Wt1 + 16384;            // 8192
    size_t off = (size_t)((char*)(Wt2 + 8192) - ws);
    off = (off + 255) & ~(size_t)255;
    unsigned short* bufA = (unsigned short*)(ws + off);  // N*128 fp16
    unsigned short* bufB = bufA + (size_t)N * 128;       // N*128 fp16

    const int* esrc = edges;
    const int* edst = edges + E;

    // CSR build
    prep_weights<<<160, 256, 0, stream>>>(W0, W1, W2, Wt0, Wt1, Wt2, bcount);
    scatter_bump<<<NPART, 256, 0, stream>>>(esrc, edst, bcount, P, E);
    bucket_build<<<NB2, 256, 0, stream>>>(P, bcount, offs2, dinv, csr, N);

    const int gemmBlocks = (N + 127) / 128;       // 782
    const int aggBlocks = (N + 3) / 4;            // 25000
    const int c32Blocks = 4 * ((N + 15) / 16);    // 25000

    // layer 0: row-major gather with NONTEMPORAL loads (A-side of probe)
    gemm_mfma<128, true, 0><<<gemmBlocks, 256, 0, stream>>>(feat, Wt0, dinv, bufA, N);
    agg128_f16<true><<<aggBlocks, 256, 0, stream>>>(bufA, csr, offs2, dinv, b0, bufB, N);
    // layer 1: 32-feature chunk slabs, 2-XCD-affine (B-side of probe)
    gemm_mfma<128, false, 1><<<gemmBlocks, 256, 0, stream>>>(bufB, Wt1, dinv, bufA, N);
    agg128_c32<<<c32Blocks, 256, 0, stream>>>(bufA, csr, offs2, dinv, b1, bufB, N);
    // layer 2 + log_softmax (row-major output, unchanged softmax kernel)
    gemm_mfma<64, false, 0><<<gemmBlocks, 256, 0, stream>>>(bufB, Wt2, dinv, bufA, N);
    agg_softmax64_f16<<<aggBlocks, 256, 0, stream>>>(bufA, csr, offs2, dinv, b2, (float*)d_out, N);
}

// Round 4
// 372.572 us; speedup vs baseline: 1.4247x; 1.2171x over previous
//
#include <hip/hip_runtime.h>
#include <hip/hip_fp16.h>
#include <math.h>

// StackedGCN: N=100000, E=1600000, 128 -> 128 -> 128 -> 64, fp32 in/out.
// FP16 activation pipeline, fp32 MFMA accumulation, dinv prescaled in GEMM
// epilogue. Aggregation: row-major 256B-row gather (verified 63.3 us/agg;
// XCD-affine chunking and NT loads both measured slower - the gather obeys
// a ~110 G granule/s service law regardless of residence tier).
// Round-4 change: GEMM loads A fragments directly from global into MFMA
// registers (A rows map 1:1 to lanes; 4 lanes x 16B = full 64B granules),
// removing the 35KB sA stage + one barrier. LDS 70->35KB = 4 blocks/CU.
#define NN 100000
#define EE 1600000
#define NB2 782     // dst buckets: dst>>7 -> 128 nodes per bucket
#define BN 128      // nodes per bucket
#define NPART 512   // scatter_bump blocks
#define CAP 2560    // padded segment capacity (mean 2048, sd ~45 -> +11 sigma)

typedef __attribute__((ext_vector_type(8))) _Float16 half8;
typedef __attribute__((ext_vector_type(4))) float f32x4;
typedef __attribute__((ext_vector_type(4))) unsigned int u32x4;

__device__ inline unsigned short f2h(float x) {
    return __half_as_ushort(__float2half(x));
}
__device__ inline __half2 u2h2(unsigned u) {
    return __builtin_bit_cast(__half2, u);
}
__device__ inline unsigned h22u(__half2 h) {
    return __builtin_bit_cast(unsigned, h);
}

// ---------------- weight prep (+ bcount zero) ----------------

__global__ void prep_weights(const float* __restrict__ W0, const float* __restrict__ W1,
                             const float* __restrict__ W2, unsigned short* __restrict__ Wt0,
                             unsigned short* __restrict__ Wt1, unsigned short* __restrict__ Wt2,
                             int* __restrict__ bcount) {
    int g = blockIdx.x * 256 + threadIdx.x;
    if (g < NB2) bcount[g] = 0;
    if (g < 16384) {
        int n = g >> 7, k = g & 127;
        Wt0[g] = f2h(W0[k * 128 + n]);
    } else if (g < 32768) {
        int i = g - 16384;
        int n = i >> 7, k = i & 127;
        Wt1[i] = f2h(W1[k * 128 + n]);
    } else if (g < 40960) {
        int i = g - 32768;
        int n = i >> 7, k = i & 127;
        Wt2[i] = f2h(W2[k * 64 + n]);
    }
}

// ---------------- CSR build ----------------

__global__ __launch_bounds__(256) void scatter_bump(const int* __restrict__ src,
                                                    const int* __restrict__ dst,
                                                    int* __restrict__ bcount,
                                                    int* __restrict__ P, int e) {
    __shared__ int cnt[NB2];
    __shared__ int basep[NB2];
    __shared__ int cur[NB2];
    int t = threadIdx.x;
    for (int i = t; i < NB2; i += 256) { cnt[i] = 0; cur[i] = 0; }
    __syncthreads();
    int chunk = (e + NPART - 1) / NPART;
    int b0 = blockIdx.x * chunk, b1 = min(e, b0 + chunk);
    for (int i = b0 + t; i < b1; i += 256)
        atomicAdd(&cnt[dst[i] >> 7], 1);
    __syncthreads();
    for (int i = t; i < NB2; i += 256) {
        int c = cnt[i];
        basep[i] = c ? atomicAdd(&bcount[i], c) : 0;
    }
    __syncthreads();
    for (int i = b0 + t; i < b1; i += 256) {  // second read is L2-hot
        int d = dst[i];
        int b = d >> 7;
        int p = basep[b] + atomicAdd(&cur[b], 1);
        P[(size_t)b * CAP + p] = (src[i] << 7) | (d & 127);  // src<2^17: 24 bits
    }
}

__global__ __launch_bounds__(256) void bucket_build(const int* __restrict__ P,
                                                    const int* __restrict__ bcount,
                                                    int2* __restrict__ offs2,
                                                    float* __restrict__ dinv,
                                                    int* __restrict__ csr, int n) {
    __shared__ int cnt[BN];
    __shared__ int sc[BN];
    __shared__ int cur[BN];
    __shared__ int stage[CAP];
    int b = blockIdx.x, t = threadIdx.x;
    int base = b * CAP;
    int count = bcount[b];
    if (t < BN) cnt[t] = 0;
    __syncthreads();
    for (int i = t; i < count; i += 256)
        atomicAdd(&cnt[P[base + i] & 127], 1);
    __syncthreads();
    int v = 0;
    if (t < BN) {
        v = cnt[t];
        sc[t] = v;
    }
    for (int d = 1; d < BN; d <<= 1) {
        __syncthreads();
        int x = (t < BN && t >= d) ? sc[t - d] : 0;
        __syncthreads();
        if (t < BN) sc[t] += x;
    }
    __syncthreads();
    if (t < BN) {
        int myoff = sc[t] - v;
        int node = b * BN + t;
        if (node < n) {
            offs2[node] = make_int2(base + myoff, base + myoff + v);
            dinv[node] = 1.0f / sqrtf((float)(v + 1));  // +1 self-loop
        }
        cur[t] = myoff;
    }
    __syncthreads();
    for (int i = t; i < count; i += 256) {  // second read L2-hot
        int pe = P[base + i];
        int p = atomicAdd(&cur[pe & 127], 1);
        stage[p] = ((unsigned)pe) >> 7;     // p < count <= CAP always
    }
    __syncthreads();
    for (int i = t; i < count; i += 256) csr[base + i] = stage[i];
}

// ---------------- MFMA GEMM (f16) + dinv-prescale epilogue ----------------
// A fragments loaded DIRECTLY from global (no sA staging): for the
// 16x16x32 MFMA, lane (m0,kq) needs A[row][kq..kq+7] - 4 lanes per row read
// a contiguous 64B granule -> fully coalesced. LDS holds only the B tile.
template <bool F32>
__device__ inline half8 load_a(const void* A, int row, int col, int nrows) {
    if (row >= nrows) {
        u32x4 z = {0u, 0u, 0u, 0u};
        return __builtin_bit_cast(half8, z);
    }
    if (F32) {
        const float* p = (const float*)A + (size_t)row * 128 + col;
        float4 v0 = *(const float4*)p;
        float4 v1 = *(const float4*)(p + 4);
        u32x4 u;
        u.x = h22u(__floats2half2_rn(v0.x, v0.y));
        u.y = h22u(__floats2half2_rn(v0.z, v0.w));
        u.z = h22u(__floats2half2_rn(v1.x, v1.y));
        u.w = h22u(__floats2half2_rn(v1.z, v1.w));
        return __builtin_bit_cast(half8, u);
    } else {
        const unsigned short* p = (const unsigned short*)A + (size_t)row * 128 + col;
        u32x4 u = *(const u32x4*)p;
        return __builtin_bit_cast(half8, u);
    }
}

template <int DOUT, bool A_IS_F32>
__global__ __launch_bounds__(256) void gemm_mfma(const void* __restrict__ Aptr,
                                                 const unsigned short* __restrict__ Wt,
                                                 const float* __restrict__ dinv,
                                                 unsigned short* __restrict__ Y, int nrows) {
    constexpr int KP = 136;
    constexpr int NT = DOUT / 16;
    __shared__ unsigned short sB[DOUT * KP];
    const int row0 = blockIdx.x * 128;
    const int tid = threadIdx.x;

    for (int i = tid; i < DOUT * 16; i += 256) {
        int n = i >> 4, c = (i & 15) * 8;
        uint4 v = *(const uint4*)(Wt + n * 128 + c);
        *(uint4*)(&sB[n * KP + c]) = v;
    }
    __syncthreads();

    const int wave = tid >> 6;
    const int lane = tid & 63;
    const int m0 = lane & 15;
    const int kq = (lane >> 4) * 8;
    const int ar0 = row0 + wave * 32 + m0;
    const int ar1 = ar0 + 16;

    f32x4 acc[2][NT];
#pragma unroll
    for (int rt = 0; rt < 2; ++rt)
#pragma unroll
        for (int t = 0; t < NT; ++t) acc[rt][t] = (f32x4){0.f, 0.f, 0.f, 0.f};

#pragma unroll
    for (int k0 = 0; k0 < 128; k0 += 32) {
        half8 a0 = load_a<A_IS_F32>(Aptr, ar0, k0 + kq, nrows);
        half8 a1 = load_a<A_IS_F32>(Aptr, ar1, k0 + kq, nrows);
#pragma unroll
        for (int t = 0; t < NT; ++t) {
            half8 b = *(const half8*)(&sB[(t * 16 + m0) * KP + k0 + kq]);
            acc[0][t] = __builtin_amdgcn_mfma_f32_16x16x32_f16(a0, b, acc[0][t], 0, 0, 0);
            acc[1][t] = __builtin_amdgcn_mfma_f32_16x16x32_f16(a1, b, acc[1][t], 0, 0, 0);
        }
    }

    // C/D layout: col = lane&15, row = (lane>>4)*4 + reg (dtype-independent)
#pragma unroll
    for (int rt = 0; rt < 2; ++rt)
#pragma unroll
        for (int r = 0; r < 4; ++r) {
            int row = row0 + wave * 32 + rt * 16 + (lane >> 4) * 4 + r;
            if (row < nrows) {
                float dv = dinv[row];
#pragma unroll
                for (int t = 0; t < NT; ++t)
                    Y[(size_t)row * DOUT + t * 16 + (lane & 15)] = f2h(acc[rt][t][r] * dv);
            }
        }
}

// ---------------- aggregation D=128: LDS-staged list, packed fp16 accumulation ----------------
__global__ __launch_bounds__(256) void agg128_f16(const unsigned short* __restrict__ Xp,
                                                  const int* __restrict__ csr,
                                                  const int2* __restrict__ offs2,
                                                  const float* __restrict__ dinv,
                                                  const float* __restrict__ bias,
                                                  unsigned short* __restrict__ Y, int n) {
    __shared__ int sIdx[4][64];
    int wv = threadIdx.x >> 6;
    int node = blockIdx.x * 4 + wv;
    if (node >= n) return;
    int lane = threadIdx.x & 63;
    int q = lane >> 4;
    int l = lane & 15;
    int2 se = offs2[node];
    int s = se.x, deg = se.y - se.x;
    if (lane < deg) sIdx[wv][lane] = csr[s + lane];
    int dcap = min(deg, 64);
    const int* idx = sIdx[wv];   // same-wave LDS: program-ordered, no barrier
    const __half2 hz = __floats2half2_rn(0.f, 0.f);
    __half2 aA0 = hz, aA1 = hz, aA2 = hz, aA3 = hz;   // set A: edges j, j+8
    __half2 aB0 = hz, aB1 = hz, aB2 = hz, aB3 = hz;   // set B: edges j+4, j+12
    int j = q;
    for (; j + 12 < dcap; j += 16) {  // 4 gathers in flight per quarter-wave
        int s0 = idx[j], s1 = idx[j + 4], s2 = idx[j + 8], s3 = idx[j + 12];
        uint4 u0 = *(const uint4*)(Xp + (size_t)s0 * 128 + l * 8);
        uint4 u1 = *(const uint4*)(Xp + (size_t)s1 * 128 + l * 8);
        uint4 u2 = *(const uint4*)(Xp + (size_t)s2 * 128 + l * 8);
        uint4 u3 = *(const uint4*)(Xp + (size_t)s3 * 128 + l * 8);
        aA0 = __hadd2(aA0, u2h2(u0.x)); aA1 = __hadd2(aA1, u2h2(u0.y));
        aA2 = __hadd2(aA2, u2h2(u0.z)); aA3 = __hadd2(aA3, u2h2(u0.w));
        aB0 = __hadd2(aB0, u2h2(u1.x)); aB1 = __hadd2(aB1, u2h2(u1.y));
        aB2 = __hadd2(aB2, u2h2(u1.z)); aB3 = __hadd2(aB3, u2h2(u1.w));
        aA0 = __hadd2(aA0, u2h2(u2.x)); aA1 = __hadd2(aA1, u2h2(u2.y));
        aA2 = __hadd2(aA2, u2h2(u2.z)); aA3 = __hadd2(aA3, u2h2(u2.w));
        aB0 = __hadd2(aB0, u2h2(u3.x)); aB1 = __hadd2(aB1, u2h2(u3.y));
        aB2 = __hadd2(aB2, u2h2(u3.z)); aB3 = __hadd2(aB3, u2h2(u3.w));
    }
    for (; j < dcap; j += 4) {
        int s0 = idx[j];
        uint4 u = *(const uint4*)(Xp + (size_t)s0 * 128 + l * 8);
        aA0 = __hadd2(aA0, u2h2(u.x)); aA1 = __hadd2(aA1, u2h2(u.y));
        aA2 = __hadd2(aA2, u2h2(u.z)); aA3 = __hadd2(aA3, u2h2(u.w));
    }
    for (int p = s + 64 + q; p < s + deg; p += 4) {  // deg>64 safety net
        int s0 = csr[p];
        uint4 u = *(const uint4*)(Xp + (size_t)s0 * 128 + l * 8);
        aB0 = __hadd2(aB0, u2h2(u.x)); aB1 = __hadd2(aB1, u2h2(u.y));
        aB2 = __hadd2(aB2, u2h2(u.z)); aB3 = __hadd2(aB3, u2h2(u.w));
    }
    if (q == 0) {  // self-loop row (prescaled)
        uint4 u = *(const uint4*)(Xp + (size_t)node * 128 + l * 8);
        aB0 = __hadd2(aB0, u2h2(u.x)); aB1 = __hadd2(aB1, u2h2(u.y));
        aB2 = __hadd2(aB2, u2h2(u.z)); aB3 = __hadd2(aB3, u2h2(u.w));
    }
    // combine sets in f32, then cross-lane reduce in f32
    float2 fA, fB;
    fA = __half22float2(aA0); fB = __half22float2(aB0);
    float r0 = fA.x + fB.x, r1 = fA.y + fB.y;
    fA = __half22float2(aA1); fB = __half22float2(aB1);
    float r2 = fA.x + fB.x, r3 = fA.y + fB.y;
    fA = __half22float2(aA2); fB = __half22float2(aB2);
    float r4 = fA.x + fB.x, r5 = fA.y + fB.y;
    fA = __half22float2(aA3); fB = __half22float2(aB3);
    float r6 = fA.x + fB.x, r7 = fA.y + fB.y;
    r0 += __shfl_xor(r0, 16); r0 += __shfl_xor(r0, 32);
    r1 += __shfl_xor(r1, 16); r1 += __shfl_xor(r1, 32);
    r2 += __shfl_xor(r2, 16); r2 += __shfl_xor(r2, 32);
    r3 += __shfl_xor(r3, 16); r3 += __shfl_xor(r3, 32);
    r4 += __shfl_xor(r4, 16); r4 += __shfl_xor(r4, 32);
    r5 += __shfl_xor(r5, 16); r5 += __shfl_xor(r5, 32);
    r6 += __shfl_xor(r6, 16); r6 += __shfl_xor(r6, 32);
    r7 += __shfl_xor(r7, 16); r7 += __shfl_xor(r7, 32);
    if (q == 0) {
        float di = dinv[node];
        float4 bA = *(const float4*)(bias + l * 8);
        float4 bB = *(const float4*)(bias + l * 8 + 4);
        r0 = fmaxf(fmaf(di, r0, bA.x), 0.f); r1 = fmaxf(fmaf(di, r1, bA.y), 0.f);
        r2 = fmaxf(fmaf(di, r2, bA.z), 0.f); r3 = fmaxf(fmaf(di, r3, bA.w), 0.f);
        r4 = fmaxf(fmaf(di, r4, bB.x), 0.f); r5 = fmaxf(fmaf(di, r5, bB.y), 0.f);
        r6 = fmaxf(fmaf(di, r6, bB.z), 0.f); r7 = fmaxf(fmaf(di, r7, bB.w), 0.f);
        uint4 o;
        o.x = h22u(__floats2half2_rn(r0, r1));
        o.y = h22u(__floats2half2_rn(r2, r3));
        o.z = h22u(__floats2half2_rn(r4, r5));
        o.w = h22u(__floats2half2_rn(r6, r7));
        *(uint4*)(Y + (size_t)node * 128 + l * 8) = o;
    }
}

// ---------------- last layer D=64: packed fp16 accumulation + log_softmax ----------------
__global__ __launch_bounds__(256) void agg_softmax64_f16(const unsigned short* __restrict__ Xp,
                                                         const int* __restrict__ csr,
                                                         const int2* __restrict__ offs2,
                                                         const float* __restrict__ dinv,
                                                         const float* __restrict__ bias,
                                                         float* __restrict__ out, int n) {
    __shared__ int sIdx[4][64];
    int wv = threadIdx.x >> 6;
    int node = blockIdx.x * 4 + wv;
    if (node >= n) return;
    int lane = threadIdx.x & 63;
    int g8 = lane >> 3;
    int l = lane & 7;
    int2 se = offs2[node];
    int s = se.x, deg = se.y - se.x;
    if (lane < deg) sIdx[wv][lane] = csr[s + lane];
    int dcap = min(deg, 64);
    const int* idx = sIdx[wv];
    const __half2 hz = __floats2half2_rn(0.f, 0.f);
    __half2 aA0 = hz, aA1 = hz, aA2 = hz, aA3 = hz;
    __half2 aB0 = hz, aB1 = hz, aB2 = hz, aB3 = hz;
    int j = g8;
    for (; j + 8 < dcap; j += 16) {
        int s0 = idx[j], s1 = idx[j + 8];
        uint4 u0 = *(const uint4*)(Xp + (size_t)s0 * 64 + l * 8);
        uint4 u1 = *(const uint4*)(Xp + (size_t)s1 * 64 + l * 8);
        aA0 = __hadd2(aA0, u2h2(u0.x)); aA1 = __hadd2(aA1, u2h2(u0.y));
        aA2 = __hadd2(aA2, u2h2(u0.z)); aA3 = __hadd2(aA3, u2h2(u0.w));
        aB0 = __hadd2(aB0, u2h2(u1.x)); aB1 = __hadd2(aB1, u2h2(u1.y));
        aB2 = __hadd2(aB2, u2h2(u1.z)); aB3 = __hadd2(aB3, u2h2(u1.w));
    }
    if (j < dcap) {
        int s0 = idx[j];
        uint4 u = *(const uint4*)(Xp + (size_t)s0 * 64 + l * 8);
        aA0 = __hadd2(aA0, u2h2(u.x)); aA1 = __hadd2(aA1, u2h2(u.y));
        aA2 = __hadd2(aA2, u2h2(u.z)); aA3 = __hadd2(aA3, u2h2(u.w));
    }
    for (int p = s + 64 + g8; p < s + deg; p += 8) {  // deg>64 safety net
        int s0 = csr[p];
        uint4 u = *(const uint4*)(Xp + (size_t)s0 * 64 + l * 8);
        aB0 = __hadd2(aB0, u2h2(u.x)); aB1 = __hadd2(aB1, u2h2(u.y));
        aB2 = __hadd2(aB2, u2h2(u.z)); aB3 = __hadd2(aB3, u2h2(u.w));
    }
    if (g8 == 0) {  // self-loop
        uint4 u = *(const uint4*)(Xp + (size_t)node * 64 + l * 8);
        aB0 = __hadd2(aB0, u2h2(u.x)); aB1 = __hadd2(aB1, u2h2(u.y));
        aB2 = __hadd2(aB2, u2h2(u.z)); aB3 = __hadd2(aB3, u2h2(u.w));
    }
    float2 fA, fB;
    fA = __half22float2(aA0); fB = __half22float2(aB0);
    float r0 = fA.x + fB.x, r1 = fA.y + fB.y;
    fA = __half22float2(aA1); fB = __half22float2(aB1);
    float r2 = fA.x + fB.x, r3 = fA.y + fB.y;
    fA = __half22float2(aA2); fB = __half22float2(aB2);
    float r4 = fA.x + fB.x, r5 = fA.y + fB.y;
    fA = __half22float2(aA3); fB = __half22float2(aB3);
    float r6 = fA.x + fB.x, r7 = fA.y + fB.y;
    r0 += __shfl_xor(r0, 8); r0 += __shfl_xor(r0, 16); r0 += __shfl_xor(r0, 32);
    r1 += __shfl_xor(r1, 8); r1 += __shfl_xor(r1, 16); r1 += __shfl_xor(r1, 32);
    r2 += __shfl_xor(r2, 8); r2 += __shfl_xor(r2, 16); r2 += __shfl_xor(r2, 32);
    r3 += __shfl_xor(r3, 8); r3 += __shfl_xor(r3, 16); r3 += __shfl_xor(r3, 32);
    r4 += __shfl_xor(r4, 8); r4 += __shfl_xor(r4, 16); r4 += __shfl_xor(r4, 32);
    r5 += __shfl_xor(r5, 8); r5 += __shfl_xor(r5, 16); r5 += __shfl_xor(r5, 32);
    r6 += __shfl_xor(r6, 8); r6 += __shfl_xor(r6, 16); r6 += __shfl_xor(r6, 32);
    r7 += __shfl_xor(r7, 8); r7 += __shfl_xor(r7, 16); r7 += __shfl_xor(r7, 32);
    if (g8 == 0) {
        float di = dinv[node];
        float4 bA = *(const float4*)(bias + l * 8);
        float4 bB = *(const float4*)(bias + l * 8 + 4);
        r0 = fmaf(di, r0, bA.x); r1 = fmaf(di, r1, bA.y);
        r2 = fmaf(di, r2, bA.z); r3 = fmaf(di, r3, bA.w);
        r4 = fmaf(di, r4, bB.x); r5 = fmaf(di, r5, bB.y);
        r6 = fmaf(di, r6, bB.z); r7 = fmaf(di, r7, bB.w);
        float m = fmaxf(fmaxf(fmaxf(r0, r1), fmaxf(r2, r3)), fmaxf(fmaxf(r4, r5), fmaxf(r6, r7)));
#pragma unroll
        for (int o = 4; o > 0; o >>= 1) m = fmaxf(m, __shfl_xor(m, o));
        float ssum = __expf(r0 - m) + __expf(r1 - m) + __expf(r2 - m) + __expf(r3 - m) +
                     __expf(r4 - m) + __expf(r5 - m) + __expf(r6 - m) + __expf(r7 - m);
#pragma unroll
        for (int o = 4; o > 0; o >>= 1) ssum += __shfl_xor(ssum, o);
        float lg = m + __logf(ssum);
        float4 o0 = make_float4(r0 - lg, r1 - lg, r2 - lg, r3 - lg);
        float4 o1 = make_float4(r4 - lg, r5 - lg, r6 - lg, r7 - lg);
        *(float4*)(out + (size_t)node * 64 + l * 8) = o0;
        *(float4*)(out + (size_t)node * 64 + l * 8 + 4) = o1;
    }
}

// ---------------- launcher ----------------

extern "C" void kernel_launch(void* const* d_in, const int* in_sizes, int n_in,
                              void* d_out, int out_size, void* d_ws, size_t ws_size,
                              hipStream_t stream) {
    const int* edges = (const int*)d_in[0];
    const float* feat = (const float*)d_in[1];
    const float* W0 = (const float*)d_in[2];
    const float* b0 = (const float*)d_in[3];
    const float* W1 = (const float*)d_in[4];
    const float* b1 = (const float*)d_in[5];
    const float* W2 = (const float*)d_in[6];
    const float* b2 = (const float*)d_in[7];

    const int N = NN;
    const int E = EE;

    char* ws = (char*)d_ws;
    int* bcount = (int*)ws;                       // NB2
    int2* offs2 = (int2*)(bcount + ((NB2 + 1) & ~1));  // N (8B aligned)
    float* dinv = (float*)(offs2 + N);            // N
    int* P = (int*)(dinv + N);                    // NB2*CAP (packed src<<7|dst&127)
    int* csr = P + (size_t)NB2 * CAP;             // NB2*CAP (src only)
    unsigned short* Wt0 = (unsigned short*)(csr + (size_t)NB2 * CAP);  // 16384
    unsigned short* Wt1 = Wt0 + 16384;            // 16384
    unsigned short* Wt2 = Wt1 + 16384;            // 8192
    size_t off = (size_t)((char*)(Wt2 + 8192) - ws);
    off = (off + 255) & ~(size_t)255;
    unsigned short* bufA = (unsigned short*)(ws + off);  // N*128 fp16
    unsigned short* bufB = bufA + (size_t)N * 128;       // N*128 fp16

    const int* esrc = edges;
    const int* edst = edges + E;

    // CSR build
    prep_weights<<<160, 256, 0, stream>>>(W0, W1, W2, Wt0, Wt1, Wt2, bcount);
    scatter_bump<<<NPART, 256, 0, stream>>>(esrc, edst, bcount, P, E);
    bucket_build<<<NB2, 256, 0, stream>>>(P, bcount, offs2, dinv, csr, N);

    const int gemmBlocks = (N + 127) / 128;  // 782
    const int aggBlocks = (N + 3) / 4;       // 25000

    // layer 0
    gemm_mfma<128, true><<<gemmBlocks, 256, 0, stream>>>(feat, Wt0, dinv, bufA, N);
    agg128_f16<<<aggBlocks, 256, 0, stream>>>(bufA, csr, offs2, dinv, b0, bufB, N);
    // layer 1
    gemm_mfma<128, false><<<gemmBlocks, 256, 0, stream>>>(bufB, Wt1, dinv, bufA, N);
    agg128_f16<<<aggBlocks, 256, 0, stream>>>(bufA, csr, offs2, dinv, b1, bufB, N);
    // layer 2 + log_softmax
    gemm_mfma<64, false><<<gemmBlocks, 256, 0, stream>>>(bufB, Wt2, dinv, bufA, N);
    agg_softmax64_f16<<<aggBlocks, 256, 0, stream>>>(bufA, csr, offs2, dinv, b2, (float*)d_out, N);
}

// Round 6
// 372.016 us; speedup vs baseline: 1.4269x; 1.0015x over previous
//
#include <hip/hip_runtime.h>
#include <hip/hip_fp16.h>
#include <math.h>

// StackedGCN: N=100000, E=1600000, 128 -> 128 -> 128 -> 64, fp32 in/out.
// FP16 activation pipeline, fp32 MFMA accumulation, dinv prescaled in GEMM
// epilogue. Aggregation: row-major 256B-row gather (63.3 us/agg = structural
// floor of the ~110 G granule/s random-gather service law; affinity/NT
// variants all measured slower).
// Round-6: cooperative CSR fusion REVERTED (suspected graph-capture hang).
// Single change vs the verified 372.6 us kernel: GEMM operand swap
// (A=W-tile from LDS, B=X rows from global). Fragment layouts are symmetric
// so loads are identical; D now has out-features in the register index ->
// packed 8B epilogue stores (16/thread vs 64 scalar 2B) + 1 dinv load/row.
#define NN 100000
#define EE 1600000
#define NB2 782     // dst buckets: dst>>7 -> 128 nodes per bucket
#define BN 128      // nodes per bucket
#define NPART 512   // scatter_bump blocks
#define CAP 2560    // padded segment capacity (mean 2048, sd ~45 -> +11 sigma)

typedef __attribute__((ext_vector_type(8))) _Float16 half8;
typedef __attribute__((ext_vector_type(4))) float f32x4;
typedef __attribute__((ext_vector_type(4))) unsigned int u32x4;

__device__ inline unsigned short f2h(float x) {
    return __half_as_ushort(__float2half(x));
}
__device__ inline __half2 u2h2(unsigned u) {
    return __builtin_bit_cast(__half2, u);
}
__device__ inline unsigned h22u(__half2 h) {
    return __builtin_bit_cast(unsigned, h);
}

// ---------------- weight prep (+ bcount zero) ----------------

__global__ void prep_weights(const float* __restrict__ W0, const float* __restrict__ W1,
                             const float* __restrict__ W2, unsigned short* __restrict__ Wt0,
                             unsigned short* __restrict__ Wt1, unsigned short* __restrict__ Wt2,
                             int* __restrict__ bcount) {
    int g = blockIdx.x * 256 + threadIdx.x;
    if (g < NB2) bcount[g] = 0;
    if (g < 16384) {
        int n = g >> 7, k = g & 127;
        Wt0[g] = f2h(W0[k * 128 + n]);
    } else if (g < 32768) {
        int i = g - 16384;
        int n = i >> 7, k = i & 127;
        Wt1[i] = f2h(W1[k * 128 + n]);
    } else if (g < 40960) {
        int i = g - 32768;
        int n = i >> 7, k = i & 127;
        Wt2[i] = f2h(W2[k * 64 + n]);
    }
}

// ---------------- CSR build ----------------

__global__ __launch_bounds__(256) void scatter_bump(const int* __restrict__ src,
                                                    const int* __restrict__ dst,
                                                    int* __restrict__ bcount,
                                                    int* __restrict__ P, int e) {
    __shared__ int cnt[NB2];
    __shared__ int basep[NB2];
    __shared__ int cur[NB2];
    int t = threadIdx.x;
    for (int i = t; i < NB2; i += 256) { cnt[i] = 0; cur[i] = 0; }
    __syncthreads();
    int chunk = (e + NPART - 1) / NPART;
    int b0 = blockIdx.x * chunk, b1 = min(e, b0 + chunk);
    for (int i = b0 + t; i < b1; i += 256)
        atomicAdd(&cnt[dst[i] >> 7], 1);
    __syncthreads();
    for (int i = t; i < NB2; i += 256) {
        int c = cnt[i];
        basep[i] = c ? atomicAdd(&bcount[i], c) : 0;
    }
    __syncthreads();
    for (int i = b0 + t; i < b1; i += 256) {  // second read is L2-hot
        int d = dst[i];
        int b = d >> 7;
        int p = basep[b] + atomicAdd(&cur[b], 1);
        P[(size_t)b * CAP + p] = (src[i] << 7) | (d & 127);  // src<2^17: 24 bits
    }
}

__global__ __launch_bounds__(256) void bucket_build(const int* __restrict__ P,
                                                    const int* __restrict__ bcount,
                                                    int2* __restrict__ offs2,
                                                    float* __restrict__ dinv,
                                                    int* __restrict__ csr, int n) {
    __shared__ int cnt[BN];
    __shared__ int sc[BN];
    __shared__ int cur[BN];
    __shared__ int stage[CAP];
    int b = blockIdx.x, t = threadIdx.x;
    int base = b * CAP;
    int count = bcount[b];
    if (t < BN) cnt[t] = 0;
    __syncthreads();
    for (int i = t; i < count; i += 256)
        atomicAdd(&cnt[P[base + i] & 127], 1);
    __syncthreads();
    int v = 0;
    if (t < BN) {
        v = cnt[t];
        sc[t] = v;
    }
    for (int d = 1; d < BN; d <<= 1) {
        __syncthreads();
        int x = (t < BN && t >= d) ? sc[t - d] : 0;
        __syncthreads();
        if (t < BN) sc[t] += x;
    }
    __syncthreads();
    if (t < BN) {
        int myoff = sc[t] - v;
        int node = b * BN + t;
        if (node < n) {
            offs2[node] = make_int2(base + myoff, base + myoff + v);
            dinv[node] = 1.0f / sqrtf((float)(v + 1));  // +1 self-loop
        }
        cur[t] = myoff;
    }
    __syncthreads();
    for (int i = t; i < count; i += 256) {  // second read L2-hot
        int pe = P[base + i];
        int p = atomicAdd(&cur[pe & 127], 1);
        stage[p] = ((unsigned)pe) >> 7;     // p < count <= CAP always
    }
    __syncthreads();
    for (int i = t; i < count; i += 256) csr[base + i] = stage[i];
}

// ---------------- MFMA GEMM (f16) + dinv-prescale epilogue ----------------
// Operand swap: A := W-tile (LDS), B := X rows (global, no staging).
// B-fragment rows map 1:1 to lanes (lane&15), 4 lanes x 16B per row = full
// 64B granules. D layout: col(lane&15)=X-row, row((lane>>4)*4+r)=out-feature
// -> 4 contiguous out-features per lane -> packed 8B stores.
template <bool F32>
__device__ inline half8 load_xrow(const void* A, int row, int col, int nrows) {
    if (row >= nrows) {
        u32x4 z = {0u, 0u, 0u, 0u};
        return __builtin_bit_cast(half8, z);
    }
    if (F32) {
        const float* p = (const float*)A + (size_t)row * 128 + col;
        float4 v0 = *(const float4*)p;
        float4 v1 = *(const float4*)(p + 4);
        u32x4 u;
        u.x = h22u(__floats2half2_rn(v0.x, v0.y));
        u.y = h22u(__floats2half2_rn(v0.z, v0.w));
        u.z = h22u(__floats2half2_rn(v1.x, v1.y));
        u.w = h22u(__floats2half2_rn(v1.z, v1.w));
        return __builtin_bit_cast(half8, u);
    } else {
        const unsigned short* p = (const unsigned short*)A + (size_t)row * 128 + col;
        u32x4 u = *(const u32x4*)p;
        return __builtin_bit_cast(half8, u);
    }
}

template <int DOUT, bool A_IS_F32>
__global__ __launch_bounds__(256) void gemm_mfma(const void* __restrict__ Aptr,
                                                 const unsigned short* __restrict__ Wt,
                                                 const float* __restrict__ dinv,
                                                 unsigned short* __restrict__ Y, int nrows) {
    constexpr int KP = 136;
    constexpr int NT = DOUT / 16;
    __shared__ unsigned short sB[DOUT * KP];
    const int row0 = blockIdx.x * 128;
    const int tid = threadIdx.x;

    for (int i = tid; i < DOUT * 16; i += 256) {
        int n = i >> 4, c = (i & 15) * 8;
        uint4 v = *(const uint4*)(Wt + n * 128 + c);
        *(uint4*)(&sB[n * KP + c]) = v;
    }
    __syncthreads();

    const int wave = tid >> 6;
    const int lane = tid & 63;
    const int m0 = lane & 15;
    const int kq = (lane >> 4) * 8;
    const int xr0 = row0 + wave * 32 + m0;   // B-operand (X) rows
    const int xr1 = xr0 + 16;

    f32x4 acc[2][NT];
#pragma unroll
    for (int rt = 0; rt < 2; ++rt)
#pragma unroll
        for (int t = 0; t < NT; ++t) acc[rt][t] = (f32x4){0.f, 0.f, 0.f, 0.f};

#pragma unroll
    for (int k0 = 0; k0 < 128; k0 += 32) {
        half8 b0 = load_xrow<A_IS_F32>(Aptr, xr0, k0 + kq, nrows);
        half8 b1 = load_xrow<A_IS_F32>(Aptr, xr1, k0 + kq, nrows);
#pragma unroll
        for (int t = 0; t < NT; ++t) {
            half8 aW = *(const half8*)(&sB[(t * 16 + m0) * KP + k0 + kq]);
            acc[0][t] = __builtin_amdgcn_mfma_f32_16x16x32_f16(aW, b0, acc[0][t], 0, 0, 0);
            acc[1][t] = __builtin_amdgcn_mfma_f32_16x16x32_f16(aW, b1, acc[1][t], 0, 0, 0);
        }
    }

    // D layout: col(lane&15) = X-row within 16-block, row((lane>>4)*4+r) = out-feature
#pragma unroll
    for (int rt = 0; rt < 2; ++rt) {
        int xrow = row0 + wave * 32 + rt * 16 + m0;
        if (xrow < nrows) {
            float dv = dinv[xrow];
#pragma unroll
            for (int t = 0; t < NT; ++t) {
                uint2 o;
                o.x = h22u(__floats2half2_rn(acc[rt][t][0] * dv, acc[rt][t][1] * dv));
                o.y = h22u(__floats2half2_rn(acc[rt][t][2] * dv, acc[rt][t][3] * dv));
                *(uint2*)(Y + (size_t)xrow * DOUT + t * 16 + (lane >> 4) * 4) = o;
            }
        }
    }
}

// ---------------- aggregation D=128: LDS-staged list, packed fp16 accumulation ----------------
__global__ __launch_bounds__(256) void agg128_f16(const unsigned short* __restrict__ Xp,
                                                  const int* __restrict__ csr,
                                                  const int2* __restrict__ offs2,
                                                  const float* __restrict__ dinv,
                                                  const float* __restrict__ bias,
                                                  unsigned short* __restrict__ Y, int n) {
    __shared__ int sIdx[4][64];
    int wv = threadIdx.x >> 6;
    int node = blockIdx.x * 4 + wv;
    if (node >= n) return;
    int lane = threadIdx.x & 63;
    int q = lane >> 4;
    int l = lane & 15;
    int2 se = offs2[node];
    int s = se.x, deg = se.y - se.x;
    if (lane < deg) sIdx[wv][lane] = csr[s + lane];
    int dcap = min(deg, 64);
    const int* idx = sIdx[wv];   // same-wave LDS: program-ordered, no barrier
    const __half2 hz = __floats2half2_rn(0.f, 0.f);
    __half2 aA0 = hz, aA1 = hz, aA2 = hz, aA3 = hz;   // set A: edges j, j+8
    __half2 aB0 = hz, aB1 = hz, aB2 = hz, aB3 = hz;   // set B: edges j+4, j+12
    int j = q;
    for (; j + 12 < dcap; j += 16) {  // 4 gathers in flight per quarter-wave
        int s0 = idx[j], s1 = idx[j + 4], s2 = idx[j + 8], s3 = idx[j + 12];
        uint4 u0 = *(const uint4*)(Xp + (size_t)s0 * 128 + l * 8);
        uint4 u1 = *(const uint4*)(Xp + (size_t)s1 * 128 + l * 8);
        uint4 u2 = *(const uint4*)(Xp + (size_t)s2 * 128 + l * 8);
        uint4 u3 = *(const uint4*)(Xp + (size_t)s3 * 128 + l * 8);
        aA0 = __hadd2(aA0, u2h2(u0.x)); aA1 = __hadd2(aA1, u2h2(u0.y));
        aA2 = __hadd2(aA2, u2h2(u0.z)); aA3 = __hadd2(aA3, u2h2(u0.w));
        aB0 = __hadd2(aB0, u2h2(u1.x)); aB1 = __hadd2(aB1, u2h2(u1.y));
        aB2 = __hadd2(aB2, u2h2(u1.z)); aB3 = __hadd2(aB3, u2h2(u1.w));
        aA0 = __hadd2(aA0, u2h2(u2.x)); aA1 = __hadd2(aA1, u2h2(u2.y));
        aA2 = __hadd2(aA2, u2h2(u2.z)); aA3 = __hadd2(aA3, u2h2(u2.w));
        aB0 = __hadd2(aB0, u2h2(u3.x)); aB1 = __hadd2(aB1, u2h2(u3.y));
        aB2 = __hadd2(aB2, u2h2(u3.z)); aB3 = __hadd2(aB3, u2h2(u3.w));
    }
    for (; j < dcap; j += 4) {
        int s0 = idx[j];
        uint4 u = *(const uint4*)(Xp + (size_t)s0 * 128 + l * 8);
        aA0 = __hadd2(aA0, u2h2(u.x)); aA1 = __hadd2(aA1, u2h2(u.y));
        aA2 = __hadd2(aA2, u2h2(u.z)); aA3 = __hadd2(aA3, u2h2(u.w));
    }
    for (int p = s + 64 + q; p < s + deg; p += 4) {  // deg>64 safety net
        int s0 = csr[p];
        uint4 u = *(const uint4*)(Xp + (size_t)s0 * 128 + l * 8);
        aB0 = __hadd2(aB0, u2h2(u.x)); aB1 = __hadd2(aB1, u2h2(u.y));
        aB2 = __hadd2(aB2, u2h2(u.z)); aB3 = __hadd2(aB3, u2h2(u.w));
    }
    if (q == 0) {  // self-loop row (prescaled)
        uint4 u = *(const uint4*)(Xp + (size_t)node * 128 + l * 8);
        aB0 = __hadd2(aB0, u2h2(u.x)); aB1 = __hadd2(aB1, u2h2(u.y));
        aB2 = __hadd2(aB2, u2h2(u.z)); aB3 = __hadd2(aB3, u2h2(u.w));
    }
    // combine sets in f32, then cross-lane reduce in f32
    float2 fA, fB;
    fA = __half22float2(aA0); fB = __half22float2(aB0);
    float r0 = fA.x + fB.x, r1 = fA.y + fB.y;
    fA = __half22float2(aA1); fB = __half22float2(aB1);
    float r2 = fA.x + fB.x, r3 = fA.y + fB.y;
    fA = __half22float2(aA2); fB = __half22float2(aB2);
    float r4 = fA.x + fB.x, r5 = fA.y + fB.y;
    fA = __half22float2(aA3); fB = __half22float2(aB3);
    float r6 = fA.x + fB.x, r7 = fA.y + fB.y;
    r0 += __shfl_xor(r0, 16); r0 += __shfl_xor(r0, 32);
    r1 += __shfl_xor(r1, 16); r1 += __shfl_xor(r1, 32);
    r2 += __shfl_xor(r2, 16); r2 += __shfl_xor(r2, 32);
    r3 += __shfl_xor(r3, 16); r3 += __shfl_xor(r3, 32);
    r4 += __shfl_xor(r4, 16); r4 += __shfl_xor(r4, 32);
    r5 += __shfl_xor(r5, 16); r5 += __shfl_xor(r5, 32);
    r6 += __shfl_xor(r6, 16); r6 += __shfl_xor(r6, 32);
    r7 += __shfl_xor(r7, 16); r7 += __shfl_xor(r7, 32);
    if (q == 0) {
        float di = dinv[node];
        float4 bA = *(const float4*)(bias + l * 8);
        float4 bB = *(const float4*)(bias + l * 8 + 4);
        r0 = fmaxf(fmaf(di, r0, bA.x), 0.f); r1 = fmaxf(fmaf(di, r1, bA.y), 0.f);
        r2 = fmaxf(fmaf(di, r2, bA.z), 0.f); r3 = fmaxf(fmaf(di, r3, bA.w), 0.f);
        r4 = fmaxf(fmaf(di, r4, bB.x), 0.f); r5 = fmaxf(fmaf(di, r5, bB.y), 0.f);
        r6 = fmaxf(fmaf(di, r6, bB.z), 0.f); r7 = fmaxf(fmaf(di, r7, bB.w), 0.f);
        uint4 o;
        o.x = h22u(__floats2half2_rn(r0, r1));
        o.y = h22u(__floats2half2_rn(r2, r3));
        o.z = h22u(__floats2half2_rn(r4, r5));
        o.w = h22u(__floats2half2_rn(r6, r7));
        *(uint4*)(Y + (size_t)node * 128 + l * 8) = o;
    }
}

// ---------------- last layer D=64: packed fp16 accumulation + log_softmax ----------------
__global__ __launch_bounds__(256) void agg_softmax64_f16(const unsigned short* __restrict__ Xp,
                                                         const int* __restrict__ csr,
                                                         const int2* __restrict__ offs2,
                                                         const float* __restrict__ dinv,
                                                         const float* __restrict__ bias,
                                                         float* __restrict__ out, int n) {
    __shared__ int sIdx[4][64];
    int wv = threadIdx.x >> 6;
    int node = blockIdx.x * 4 + wv;
    if (node >= n) return;
    int lane = threadIdx.x & 63;
    int g8 = lane >> 3;
    int l = lane & 7;
    int2 se = offs2[node];
    int s = se.x, deg = se.y - se.x;
    if (lane < deg) sIdx[wv][lane] = csr[s + lane];
    int dcap = min(deg, 64);
    const int* idx = sIdx[wv];
    const __half2 hz = __floats2half2_rn(0.f, 0.f);
    __half2 aA0 = hz, aA1 = hz, aA2 = hz, aA3 = hz;
    __half2 aB0 = hz, aB1 = hz, aB2 = hz, aB3 = hz;
    int j = g8;
    for (; j + 8 < dcap; j += 16) {
        int s0 = idx[j], s1 = idx[j + 8];
        uint4 u0 = *(const uint4*)(Xp + (size_t)s0 * 64 + l * 8);
        uint4 u1 = *(const uint4*)(Xp + (size_t)s1 * 64 + l * 8);
        aA0 = __hadd2(aA0, u2h2(u0.x)); aA1 = __hadd2(aA1, u2h2(u0.y));
        aA2 = __hadd2(aA2, u2h2(u0.z)); aA3 = __hadd2(aA3, u2h2(u0.w));
        aB0 = __hadd2(aB0, u2h2(u1.x)); aB1 = __hadd2(aB1, u2h2(u1.y));
        aB2 = __hadd2(aB2, u2h2(u1.z)); aB3 = __hadd2(aB3, u2h2(u1.w));
    }
    if (j < dcap) {
        int s0 = idx[j];
        uint4 u = *(const uint4*)(Xp + (size_t)s0 * 64 + l * 8);
        aA0 = __hadd2(aA0, u2h2(u.x)); aA1 = __hadd2(aA1, u2h2(u.y));
        aA2 = __hadd2(aA2, u2h2(u.z)); aA3 = __hadd2(aA3, u2h2(u.w));
    }
    for (int p = s + 64 + g8; p < s + deg; p += 8) {  // deg>64 safety net
        int s0 = csr[p];
        uint4 u = *(const uint4*)(Xp + (size_t)s0 * 64 + l * 8);
        aB0 = __hadd2(aB0, u2h2(u.x)); aB1 = __hadd2(aB1, u2h2(u.y));
        aB2 = __hadd2(aB2, u2h2(u.z)); aB3 = __hadd2(aB3, u2h2(u.w));
    }
    if (g8 == 0) {  // self-loop
        uint4 u = *(const uint4*)(Xp + (size_t)node * 64 + l * 8);
        aB0 = __hadd2(aB0, u2h2(u.x)); aB1 = __hadd2(aB1, u2h2(u.y));
        aB2 = __hadd2(aB2, u2h2(u.z)); aB3 = __hadd2(aB3, u2h2(u.w));
    }
    float2 fA, fB;
    fA = __half22float2(aA0); fB = __half22float2(aB0);
    float r0 = fA.x + fB.x, r1 = fA.y + fB.y;
    fA = __half22float2(aA1); fB = __half22float2(aB1);
    float r2 = fA.x + fB.x, r3 = fA.y + fB.y;
    fA = __half22float2(aA2); fB = __half22float2(aB2);
    float r4 = fA.x + fB.x, r5 = fA.y + fB.y;
    fA = __half22float2(aA3); fB = __half22float2(aB3);
    float r6 = fA.x + fB.x, r7 = fA.y + fB.y;
    r0 += __shfl_xor(r0, 8); r0 += __shfl_xor(r0, 16); r0 += __shfl_xor(r0, 32);
    r1 += __shfl_xor(r1, 8); r1 += __shfl_xor(r1, 16); r1 += __shfl_xor(r1, 32);
    r2 += __shfl_xor(r2, 8); r2 += __shfl_xor(r2, 16); r2 += __shfl_xor(r2, 32);
    r3 += __shfl_xor(r3, 8); r3 += __shfl_xor(r3, 16); r3 += __shfl_xor(r3, 32);
    r4 += __shfl_xor(r4, 8); r4 += __shfl_xor(r4, 16); r4 += __shfl_xor(r4, 32);
    r5 += __shfl_xor(r5, 8); r5 += __shfl_xor(r5, 16); r5 += __shfl_xor(r5, 32);
    r6 += __shfl_xor(r6, 8); r6 += __shfl_xor(r6, 16); r6 += __shfl_xor(r6, 32);
    r7 += __shfl_xor(r7, 8); r7 += __shfl_xor(r7, 16); r7 += __shfl_xor(r7, 32);
    if (g8 == 0) {
        float di = dinv[node];
        float4 bA = *(const float4*)(bias + l * 8);
        float4 bB = *(const float4*)(bias + l * 8 + 4);
        r0 = fmaf(di, r0, bA.x); r1 = fmaf(di, r1, bA.y);
        r2 = fmaf(di, r2, bA.z); r3 = fmaf(di, r3, bA.w);
        r4 = fmaf(di, r4, bB.x); r5 = fmaf(di, r5, bB.y);
        r6 = fmaf(di, r6, bB.z); r7 = fmaf(di, r7, bB.w);
        float m = fmaxf(fmaxf(fmaxf(r0, r1), fmaxf(r2, r3)), fmaxf(fmaxf(r4, r5), fmaxf(r6, r7)));
#pragma unroll
        for (int o = 4; o > 0; o >>= 1) m = fmaxf(m, __shfl_xor(m, o));
        float ssum = __expf(r0 - m) + __expf(r1 - m) + __expf(r2 - m) + __expf(r3 - m) +
                     __expf(r4 - m) + __expf(r5 - m) + __expf(r6 - m) + __expf(r7 - m);
#pragma unroll
        for (int o = 4; o > 0; o >>= 1) ssum += __shfl_xor(ssum, o);
        float lg = m + __logf(ssum);
        float4 o0 = make_float4(r0 - lg, r1 - lg, r2 - lg, r3 - lg);
        float4 o1 = make_float4(r4 - lg, r5 - lg, r6 - lg, r7 - lg);
        *(float4*)(out + (size_t)node * 64 + l * 8) = o0;
        *(float4*)(out + (size_t)node * 64 + l * 8 + 4) = o1;
    }
}

// ---------------- launcher ----------------

extern "C" void kernel_launch(void* const* d_in, const int* in_sizes, int n_in,
                              void* d_out, int out_size, void* d_ws, size_t ws_size,
                              hipStream_t stream) {
    const int* edges = (const int*)d_in[0];
    const float* feat = (const float*)d_in[1];
    const float* W0 = (const float*)d_in[2];
    const float* b0 = (const float*)d_in[3];
    const float* W1 = (const float*)d_in[4];
    const float* b1 = (const float*)d_in[5];
    const float* W2 = (const float*)d_in[6];
    const float* b2 = (const float*)d_in[7];

    const int N = NN;
    const int E = EE;

    char* ws = (char*)d_ws;
    int* bcount = (int*)ws;                       // NB2
    int2* offs2 = (int2*)(bcount + ((NB2 + 1) & ~1));  // N (8B aligned)
    float* dinv = (float*)(offs2 + N);            // N
    int* P = (int*)(dinv + N);                    // NB2*CAP (packed src<<7|dst&127)
    int* csr = P + (size_t)NB2 * CAP;             // NB2*CAP (src only)
    unsigned short* Wt0 = (unsigned short*)(csr + (size_t)NB2 * CAP);  // 16384
    unsigned short* Wt1 = Wt0 + 16384;            // 16384
    unsigned short* Wt2 = Wt1 + 16384;            // 8192
    size_t off = (size_t)((char*)(Wt2 + 8192) - ws);
    off = (off + 255) & ~(size_t)255;
    unsigned short* bufA = (unsigned short*)(ws + off);  // N*128 fp16
    unsigned short* bufB = bufA + (size_t)N * 128;       // N*128 fp16

    const int* esrc = edges;
    const int* edst = edges + E;

    // CSR build
    prep_weights<<<160, 256, 0, stream>>>(W0, W1, W2, Wt0, Wt1, Wt2, bcount);
    scatter_bump<<<NPART, 256, 0, stream>>>(esrc, edst, bcount, P, E);
    bucket_build<<<NB2, 256, 0, stream>>>(P, bcount, offs2, dinv, csr, N);

    const int gemmBlocks = (N + 127) / 128;  // 782
    const int aggBlocks = (N + 3) / 4;       // 25000

    // layer 0
    gemm_mfma<128, true><<<gemmBlocks, 256, 0, stream>>>(feat, Wt0, dinv, bufA, N);
    agg128_f16<<<aggBlocks, 256, 0, stream>>>(bufA, csr, offs2, dinv, b0, bufB, N);
    // layer 1
    gemm_mfma<128, false><<<gemmBlocks, 256, 0, stream>>>(bufB, Wt1, dinv, bufA, N);
    agg128_f16<<<aggBlocks, 256, 0, stream>>>(bufA, csr, offs2, dinv, b1, bufB, N);
    // layer 2 + log_softmax
    gemm_mfma<64, false><<<gemmBlocks, 256, 0, stream>>>(bufB, Wt2, dinv, bufA, N);
    agg_softmax64_f16<<<aggBlocks, 256, 0, stream>>>(bufA, csr, offs2, dinv, b2, (float*)d_out, N);
}

// Round 7
// 369.260 us; speedup vs baseline: 1.4375x; 1.0075x over previous
//
#include <hip/hip_runtime.h>
#include <hip/hip_fp16.h>
#include <math.h>

// StackedGCN: N=100000, E=1600000, 128 -> 128 -> 128 -> 64, fp32 in/out.
// FP16 activation pipeline, fp32 MFMA accumulation, dinv prescaled in GEMM
// epilogue (operand-swapped GEMM: A=W-tile LDS, B=X rows global, packed 8B
// epilogue stores - verified neutral-to-equal at 372.0 us).
// Round-7 change: agg128 rewritten as SERIAL 16-LANE-GROUP gather:
//   each 16-lane group owns one node; lane l accumulates features l*8..+7
//   over ALL edges serially (uniform broadcast csr reads, 4 gathers in
//   flight). Eliminates the entire cross-lane reduce (16 shfl + 16 cvt +
//   8 adds per node), the LDS index stage, and the deg<=64 cap.
#define NN 100000
#define EE 1600000
#define NB2 782     // dst buckets: dst>>7 -> 128 nodes per bucket
#define BN 128      // nodes per bucket
#define NPART 512   // scatter_bump blocks
#define CAP 2560    // padded segment capacity (mean 2048, sd ~45 -> +11 sigma)

typedef __attribute__((ext_vector_type(8))) _Float16 half8;
typedef __attribute__((ext_vector_type(4))) float f32x4;
typedef __attribute__((ext_vector_type(4))) unsigned int u32x4;

__device__ inline unsigned short f2h(float x) {
    return __half_as_ushort(__float2half(x));
}
__device__ inline __half2 u2h2(unsigned u) {
    return __builtin_bit_cast(__half2, u);
}
__device__ inline unsigned h22u(__half2 h) {
    return __builtin_bit_cast(unsigned, h);
}

// ---------------- weight prep (+ bcount zero) ----------------

__global__ void prep_weights(const float* __restrict__ W0, const float* __restrict__ W1,
                             const float* __restrict__ W2, unsigned short* __restrict__ Wt0,
                             unsigned short* __restrict__ Wt1, unsigned short* __restrict__ Wt2,
                             int* __restrict__ bcount) {
    int g = blockIdx.x * 256 + threadIdx.x;
    if (g < NB2) bcount[g] = 0;
    if (g < 16384) {
        int n = g >> 7, k = g & 127;
        Wt0[g] = f2h(W0[k * 128 + n]);
    } else if (g < 32768) {
        int i = g - 16384;
        int n = i >> 7, k = i & 127;
        Wt1[i] = f2h(W1[k * 128 + n]);
    } else if (g < 40960) {
        int i = g - 32768;
        int n = i >> 7, k = i & 127;
        Wt2[i] = f2h(W2[k * 64 + n]);
    }
}

// ---------------- CSR build ----------------

__global__ __launch_bounds__(256) void scatter_bump(const int* __restrict__ src,
                                                    const int* __restrict__ dst,
                                                    int* __restrict__ bcount,
                                                    int* __restrict__ P, int e) {
    __shared__ int cnt[NB2];
    __shared__ int basep[NB2];
    __shared__ int cur[NB2];
    int t = threadIdx.x;
    for (int i = t; i < NB2; i += 256) { cnt[i] = 0; cur[i] = 0; }
    __syncthreads();
    int chunk = (e + NPART - 1) / NPART;
    int b0 = blockIdx.x * chunk, b1 = min(e, b0 + chunk);
    for (int i = b0 + t; i < b1; i += 256)
        atomicAdd(&cnt[dst[i] >> 7], 1);
    __syncthreads();
    for (int i = t; i < NB2; i += 256) {
        int c = cnt[i];
        basep[i] = c ? atomicAdd(&bcount[i], c) : 0;
    }
    __syncthreads();
    for (int i = b0 + t; i < b1; i += 256) {  // second read is L2-hot
        int d = dst[i];
        int b = d >> 7;
        int p = basep[b] + atomicAdd(&cur[b], 1);
        P[(size_t)b * CAP + p] = (src[i] << 7) | (d & 127);  // src<2^17: 24 bits
    }
}

__global__ __launch_bounds__(256) void bucket_build(const int* __restrict__ P,
                                                    const int* __restrict__ bcount,
                                                    int2* __restrict__ offs2,
                                                    float* __restrict__ dinv,
                                                    int* __restrict__ csr, int n) {
    __shared__ int cnt[BN];
    __shared__ int sc[BN];
    __shared__ int cur[BN];
    __shared__ int stage[CAP];
    int b = blockIdx.x, t = threadIdx.x;
    int base = b * CAP;
    int count = bcount[b];
    if (t < BN) cnt[t] = 0;
    __syncthreads();
    for (int i = t; i < count; i += 256)
        atomicAdd(&cnt[P[base + i] & 127], 1);
    __syncthreads();
    int v = 0;
    if (t < BN) {
        v = cnt[t];
        sc[t] = v;
    }
    for (int d = 1; d < BN; d <<= 1) {
        __syncthreads();
        int x = (t < BN && t >= d) ? sc[t - d] : 0;
        __syncthreads();
        if (t < BN) sc[t] += x;
    }
    __syncthreads();
    if (t < BN) {
        int myoff = sc[t] - v;
        int node = b * BN + t;
        if (node < n) {
            offs2[node] = make_int2(base + myoff, base + myoff + v);
            dinv[node] = 1.0f / sqrtf((float)(v + 1));  // +1 self-loop
        }
        cur[t] = myoff;
    }
    __syncthreads();
    for (int i = t; i < count; i += 256) {  // second read L2-hot
        int pe = P[base + i];
        int p = atomicAdd(&cur[pe & 127], 1);
        stage[p] = ((unsigned)pe) >> 7;     // p < count <= CAP always
    }
    __syncthreads();
    for (int i = t; i < count; i += 256) csr[base + i] = stage[i];
}

// ---------------- MFMA GEMM (f16) + dinv-prescale epilogue ----------------
// Operand swap: A := W-tile (LDS), B := X rows (global, no staging).
template <bool F32>
__device__ inline half8 load_xrow(const void* A, int row, int col, int nrows) {
    if (row >= nrows) {
        u32x4 z = {0u, 0u, 0u, 0u};
        return __builtin_bit_cast(half8, z);
    }
    if (F32) {
        const float* p = (const float*)A + (size_t)row * 128 + col;
        float4 v0 = *(const float4*)p;
        float4 v1 = *(const float4*)(p + 4);
        u32x4 u;
        u.x = h22u(__floats2half2_rn(v0.x, v0.y));
        u.y = h22u(__floats2half2_rn(v0.z, v0.w));
        u.z = h22u(__floats2half2_rn(v1.x, v1.y));
        u.w = h22u(__floats2half2_rn(v1.z, v1.w));
        return __builtin_bit_cast(half8, u);
    } else {
        const unsigned short* p = (const unsigned short*)A + (size_t)row * 128 + col;
        u32x4 u = *(const u32x4*)p;
        return __builtin_bit_cast(half8, u);
    }
}

template <int DOUT, bool A_IS_F32>
__global__ __launch_bounds__(256) void gemm_mfma(const void* __restrict__ Aptr,
                                                 const unsigned short* __restrict__ Wt,
                                                 const float* __restrict__ dinv,
                                                 unsigned short* __restrict__ Y, int nrows) {
    constexpr int KP = 136;
    constexpr int NT = DOUT / 16;
    __shared__ unsigned short sB[DOUT * KP];
    const int row0 = blockIdx.x * 128;
    const int tid = threadIdx.x;

    for (int i = tid; i < DOUT * 16; i += 256) {
        int n = i >> 4, c = (i & 15) * 8;
        uint4 v = *(const uint4*)(Wt + n * 128 + c);
        *(uint4*)(&sB[n * KP + c]) = v;
    }
    __syncthreads();

    const int wave = tid >> 6;
    const int lane = tid & 63;
    const int m0 = lane & 15;
    const int kq = (lane >> 4) * 8;
    const int xr0 = row0 + wave * 32 + m0;   // B-operand (X) rows
    const int xr1 = xr0 + 16;

    f32x4 acc[2][NT];
#pragma unroll
    for (int rt = 0; rt < 2; ++rt)
#pragma unroll
        for (int t = 0; t < NT; ++t) acc[rt][t] = (f32x4){0.f, 0.f, 0.f, 0.f};

#pragma unroll
    for (int k0 = 0; k0 < 128; k0 += 32) {
        half8 b0 = load_xrow<A_IS_F32>(Aptr, xr0, k0 + kq, nrows);
        half8 b1 = load_xrow<A_IS_F32>(Aptr, xr1, k0 + kq, nrows);
#pragma unroll
        for (int t = 0; t < NT; ++t) {
            half8 aW = *(const half8*)(&sB[(t * 16 + m0) * KP + k0 + kq]);
            acc[0][t] = __builtin_amdgcn_mfma_f32_16x16x32_f16(aW, b0, acc[0][t], 0, 0, 0);
            acc[1][t] = __builtin_amdgcn_mfma_f32_16x16x32_f16(aW, b1, acc[1][t], 0, 0, 0);
        }
    }

    // D layout: col(lane&15) = X-row within 16-block, row((lane>>4)*4+r) = out-feature
#pragma unroll
    for (int rt = 0; rt < 2; ++rt) {
        int xrow = row0 + wave * 32 + rt * 16 + m0;
        if (xrow < nrows) {
            float dv = dinv[xrow];
#pragma unroll
            for (int t = 0; t < NT; ++t) {
                uint2 o;
                o.x = h22u(__floats2half2_rn(acc[rt][t][0] * dv, acc[rt][t][1] * dv));
                o.y = h22u(__floats2half2_rn(acc[rt][t][2] * dv, acc[rt][t][3] * dv));
                *(uint2*)(Y + (size_t)xrow * DOUT + t * 16 + (lane >> 4) * 4) = o;
            }
        }
    }
}

// ---------------- aggregation D=128: serial 16-lane-group, no cross-lane reduce --------
// One 16-lane group per node (4 nodes/wave, 16/block). Lane l owns features
// l*8..l*8+7 and accumulates them over ALL edges serially (csr index is
// uniform per group -> broadcast loads; 4 gathers in flight via dual fp16
// accumulator sets). No shuffles, no LDS, no deg cap; every lane stores 16B.
__global__ __launch_bounds__(256) void agg128_f16(const unsigned short* __restrict__ Xp,
                                                  const int* __restrict__ csr,
                                                  const int2* __restrict__ offs2,
                                                  const float* __restrict__ dinv,
                                                  const float* __restrict__ bias,
                                                  unsigned short* __restrict__ Y, int n) {
    const int tid = threadIdx.x;
    const int node = blockIdx.x * 16 + (tid >> 4);
    if (node >= n) return;
    const int l = tid & 15;
    const unsigned short* __restrict__ Xl = Xp + l * 8;

    int2 se = offs2[node];
    int s = se.x, deg = se.y - se.x;
    const __half2 hz = __floats2half2_rn(0.f, 0.f);
    __half2 aA0 = hz, aA1 = hz, aA2 = hz, aA3 = hz;   // edges j, j+1
    __half2 aB0 = hz, aB1 = hz, aB2 = hz, aB3 = hz;   // edges j+2, j+3
    int j = 0;
    for (; j + 4 <= deg; j += 4) {   // 4 gathers in flight, uniform csr reads
        int i0 = csr[s + j], i1 = csr[s + j + 1], i2 = csr[s + j + 2], i3 = csr[s + j + 3];
        uint4 u0 = *(const uint4*)(Xl + (size_t)i0 * 128);
        uint4 u1 = *(const uint4*)(Xl + (size_t)i1 * 128);
        uint4 u2 = *(const uint4*)(Xl + (size_t)i2 * 128);
        uint4 u3 = *(const uint4*)(Xl + (size_t)i3 * 128);
        aA0 = __hadd2(aA0, u2h2(u0.x)); aA1 = __hadd2(aA1, u2h2(u0.y));
        aA2 = __hadd2(aA2, u2h2(u0.z)); aA3 = __hadd2(aA3, u2h2(u0.w));
        aB0 = __hadd2(aB0, u2h2(u2.x)); aB1 = __hadd2(aB1, u2h2(u2.y));
        aB2 = __hadd2(aB2, u2h2(u2.z)); aB3 = __hadd2(aB3, u2h2(u2.w));
        aA0 = __hadd2(aA0, u2h2(u1.x)); aA1 = __hadd2(aA1, u2h2(u1.y));
        aA2 = __hadd2(aA2, u2h2(u1.z)); aA3 = __hadd2(aA3, u2h2(u1.w));
        aB0 = __hadd2(aB0, u2h2(u3.x)); aB1 = __hadd2(aB1, u2h2(u3.y));
        aB2 = __hadd2(aB2, u2h2(u3.z)); aB3 = __hadd2(aB3, u2h2(u3.w));
    }
    for (; j < deg; ++j) {
        int i0 = csr[s + j];
        uint4 u = *(const uint4*)(Xl + (size_t)i0 * 128);
        aA0 = __hadd2(aA0, u2h2(u.x)); aA1 = __hadd2(aA1, u2h2(u.y));
        aA2 = __hadd2(aA2, u2h2(u.z)); aA3 = __hadd2(aA3, u2h2(u.w));
    }
    {   // self-loop row (prescaled); each lane adds its own feature slice
        uint4 u = *(const uint4*)(Xl + (size_t)node * 128);
        aB0 = __hadd2(aB0, u2h2(u.x)); aB1 = __hadd2(aB1, u2h2(u.y));
        aB2 = __hadd2(aB2, u2h2(u.z)); aB3 = __hadd2(aB3, u2h2(u.w));
    }
    // combine sets in f32, scale+bias+relu, pack, one 16B store per lane
    float di = dinv[node];
    float4 bA = *(const float4*)(bias + l * 8);
    float4 bB = *(const float4*)(bias + l * 8 + 4);
    float2 fA, fB;
    fA = __half22float2(aA0); fB = __half22float2(aB0);
    float r0 = fA.x + fB.x, r1 = fA.y + fB.y;
    fA = __half22float2(aA1); fB = __half22float2(aB1);
    float r2 = fA.x + fB.x, r3 = fA.y + fB.y;
    fA = __half22float2(aA2); fB = __half22float2(aB2);
    float r4 = fA.x + fB.x, r5 = fA.y + fB.y;
    fA = __half22float2(aA3); fB = __half22float2(aB3);
    float r6 = fA.x + fB.x, r7 = fA.y + fB.y;
    r0 = fmaxf(fmaf(di, r0, bA.x), 0.f); r1 = fmaxf(fmaf(di, r1, bA.y), 0.f);
    r2 = fmaxf(fmaf(di, r2, bA.z), 0.f); r3 = fmaxf(fmaf(di, r3, bA.w), 0.f);
    r4 = fmaxf(fmaf(di, r4, bB.x), 0.f); r5 = fmaxf(fmaf(di, r5, bB.y), 0.f);
    r6 = fmaxf(fmaf(di, r6, bB.z), 0.f); r7 = fmaxf(fmaf(di, r7, bB.w), 0.f);
    uint4 o;
    o.x = h22u(__floats2half2_rn(r0, r1));
    o.y = h22u(__floats2half2_rn(r2, r3));
    o.z = h22u(__floats2half2_rn(r4, r5));
    o.w = h22u(__floats2half2_rn(r6, r7));
    *(uint4*)(Y + (size_t)node * 128 + l * 8) = o;
}

// ---------------- last layer D=64: packed fp16 accumulation + log_softmax ----------------
__global__ __launch_bounds__(256) void agg_softmax64_f16(const unsigned short* __restrict__ Xp,
                                                         const int* __restrict__ csr,
                                                         const int2* __restrict__ offs2,
                                                         const float* __restrict__ dinv,
                                                         const float* __restrict__ bias,
                                                         float* __restrict__ out, int n) {
    __shared__ int sIdx[4][64];
    int wv = threadIdx.x >> 6;
    int node = blockIdx.x * 4 + wv;
    if (node >= n) return;
    int lane = threadIdx.x & 63;
    int g8 = lane >> 3;
    int l = lane & 7;
    int2 se = offs2[node];
    int s = se.x, deg = se.y - se.x;
    if (lane < deg) sIdx[wv][lane] = csr[s + lane];
    int dcap = min(deg, 64);
    const int* idx = sIdx[wv];
    const __half2 hz = __floats2half2_rn(0.f, 0.f);
    __half2 aA0 = hz, aA1 = hz, aA2 = hz, aA3 = hz;
    __half2 aB0 = hz, aB1 = hz, aB2 = hz, aB3 = hz;
    int j = g8;
    for (; j + 8 < dcap; j += 16) {
        int s0 = idx[j], s1 = idx[j + 8];
        uint4 u0 = *(const uint4*)(Xp + (size_t)s0 * 64 + l * 8);
        uint4 u1 = *(const uint4*)(Xp + (size_t)s1 * 64 + l * 8);
        aA0 = __hadd2(aA0, u2h2(u0.x)); aA1 = __hadd2(aA1, u2h2(u0.y));
        aA2 = __hadd2(aA2, u2h2(u0.z)); aA3 = __hadd2(aA3, u2h2(u0.w));
        aB0 = __hadd2(aB0, u2h2(u1.x)); aB1 = __hadd2(aB1, u2h2(u1.y));
        aB2 = __hadd2(aB2, u2h2(u1.z)); aB3 = __hadd2(aB3, u2h2(u1.w));
    }
    if (j < dcap) {
        int s0 = idx[j];
        uint4 u = *(const uint4*)(Xp + (size_t)s0 * 64 + l * 8);
        aA0 = __hadd2(aA0, u2h2(u.x)); aA1 = __hadd2(aA1, u2h2(u.y));
        aA2 = __hadd2(aA2, u2h2(u.z)); aA3 = __hadd2(aA3, u2h2(u.w));
    }
    for (int p = s + 64 + g8; p < s + deg; p += 8) {  // deg>64 safety net
        int s0 = csr[p];
        uint4 u = *(const uint4*)(Xp + (size_t)s0 * 64 + l * 8);
        aB0 = __hadd2(aB0, u2h2(u.x)); aB1 = __hadd2(aB1, u2h2(u.y));
        aB2 = __hadd2(aB2, u2h2(u.z)); aB3 = __hadd2(aB3, u2h2(u.w));
    }
    if (g8 == 0) {  // self-loop
        uint4 u = *(const uint4*)(Xp + (size_t)node * 64 + l * 8);
        aB0 = __hadd2(aB0, u2h2(u.x)); aB1 = __hadd2(aB1, u2h2(u.y));
        aB2 = __hadd2(aB2, u2h2(u.z)); aB3 = __hadd2(aB3, u2h2(u.w));
    }
    float2 fA, fB;
    fA = __half22float2(aA0); fB = __half22float2(aB0);
    float r0 = fA.x + fB.x, r1 = fA.y + fB.y;
    fA = __half22float2(aA1); fB = __half22float2(aB1);
    float r2 = fA.x + fB.x, r3 = fA.y + fB.y;
    fA = __half22float2(aA2); fB = __half22float2(aB2);
    float r4 = fA.x + fB.x, r5 = fA.y + fB.y;
    fA = __half22float2(aA3); fB = __half22float2(aB3);
    float r6 = fA.x + fB.x, r7 = fA.y + fB.y;
    r0 += __shfl_xor(r0, 8); r0 += __shfl_xor(r0, 16); r0 += __shfl_xor(r0, 32);
    r1 += __shfl_xor(r1, 8); r1 += __shfl_xor(r1, 16); r1 += __shfl_xor(r1, 32);
    r2 += __shfl_xor(r2, 8); r2 += __shfl_xor(r2, 16); r2 += __shfl_xor(r2, 32);
    r3 += __shfl_xor(r3, 8); r3 += __shfl_xor(r3, 16); r3 += __shfl_xor(r3, 32);
    r4 += __shfl_xor(r4, 8); r4 += __shfl_xor(r4, 16); r4 += __shfl_xor(r4, 32);
    r5 += __shfl_xor(r5, 8); r5 += __shfl_xor(r5, 16); r5 += __shfl_xor(r5, 32);
    r6 += __shfl_xor(r6, 8); r6 += __shfl_xor(r6, 16); r6 += __shfl_xor(r6, 32);
    r7 += __shfl_xor(r7, 8); r7 += __shfl_xor(r7, 16); r7 += __shfl_xor(r7, 32);
    if (g8 == 0) {
        float di = dinv[node];
        float4 bA = *(const float4*)(bias + l * 8);
        float4 bB = *(const float4*)(bias + l * 8 + 4);
        r0 = fmaf(di, r0, bA.x); r1 = fmaf(di, r1, bA.y);
        r2 = fmaf(di, r2, bA.z); r3 = fmaf(di, r3, bA.w);
        r4 = fmaf(di, r4, bB.x); r5 = fmaf(di, r5, bB.y);
        r6 = fmaf(di, r6, bB.z); r7 = fmaf(di, r7, bB.w);
        float m = fmaxf(fmaxf(fmaxf(r0, r1), fmaxf(r2, r3)), fmaxf(fmaxf(r4, r5), fmaxf(r6, r7)));
#pragma unroll
        for (int o = 4; o > 0; o >>= 1) m = fmaxf(m, __shfl_xor(m, o));
        float ssum = __expf(r0 - m) + __expf(r1 - m) + __expf(r2 - m) + __expf(r3 - m) +
                     __expf(r4 - m) + __expf(r5 - m) + __expf(r6 - m) + __expf(r7 - m);
#pragma unroll
        for (int o = 4; o > 0; o >>= 1) ssum += __shfl_xor(ssum, o);
        float lg = m + __logf(ssum);
        float4 o0 = make_float4(r0 - lg, r1 - lg, r2 - lg, r3 - lg);
        float4 o1 = make_float4(r4 - lg, r5 - lg, r6 - lg, r7 - lg);
        *(float4*)(out + (size_t)node * 64 + l * 8) = o0;
        *(float4*)(out + (size_t)node * 64 + l * 8 + 4) = o1;
    }
}

// ---------------- launcher ----------------

extern "C" void kernel_launch(void* const* d_in, const int* in_sizes, int n_in,
                              void* d_out, int out_size, void* d_ws, size_t ws_size,
                              hipStream_t stream) {
    const int* edges = (const int*)d_in[0];
    const float* feat = (const float*)d_in[1];
    const float* W0 = (const float*)d_in[2];
    const float* b0 = (const float*)d_in[3];
    const float* W1 = (const float*)d_in[4];
    const float* b1 = (const float*)d_in[5];
    const float* W2 = (const float*)d_in[6];
    const float* b2 = (const float*)d_in[7];

    const int N = NN;
    const int E = EE;

    char* ws = (char*)d_ws;
    int* bcount = (int*)ws;                       // NB2
    int2* offs2 = (int2*)(bcount + ((NB2 + 1) & ~1));  // N (8B aligned)
    float* dinv = (float*)(offs2 + N);            // N
    int* P = (int*)(dinv + N);                    // NB2*CAP (packed src<<7|dst&127)
    int* csr = P + (size_t)NB2 * CAP;             // NB2*CAP (src only)
    unsigned short* Wt0 = (unsigned short*)(csr + (size_t)NB2 * CAP);  // 16384
    unsigned short* Wt1 = Wt0 + 16384;            // 16384
    unsigned short* Wt2 = Wt1 + 16384;            // 8192
    size_t off = (size_t)((char*)(Wt2 + 8192) - ws);
    off = (off + 255) & ~(size_t)255;
    unsigned short* bufA = (unsigned short*)(ws + off);  // N*128 fp16
    unsigned short* bufB = bufA + (size_t)N * 128;       // N*128 fp16

    const int* esrc = edges;
    const int* edst = edges + E;

    // CSR build
    prep_weights<<<160, 256, 0, stream>>>(W0, W1, W2, Wt0, Wt1, Wt2, bcount);
    scatter_bump<<<NPART, 256, 0, stream>>>(esrc, edst, bcount, P, E);
    bucket_build<<<NB2, 256, 0, stream>>>(P, bcount, offs2, dinv, csr, N);

    const int gemmBlocks = (N + 127) / 128;   // 782
    const int agg128Blocks = (N + 15) / 16;   // 6250
    const int aggBlocks = (N + 3) / 4;        // 25000

    // layer 0
    gemm_mfma<128, true><<<gemmBlocks, 256, 0, stream>>>(feat, Wt0, dinv, bufA, N);
    agg128_f16<<<agg128Blocks, 256, 0, stream>>>(bufA, csr, offs2, dinv, b0, bufB, N);
    // layer 1
    gemm_mfma<128, false><<<gemmBlocks, 256, 0, stream>>>(bufB, Wt1, dinv, bufA, N);
    agg128_f16<<<agg128Blocks, 256, 0, stream>>>(bufA, csr, offs2, dinv, b1, bufB, N);
    // layer 2 + log_softmax
    gemm_mfma<64, false><<<gemmBlocks, 256, 0, stream>>>(bufB, Wt2, dinv, bufA, N);
    agg_softmax64_f16<<<aggBlocks, 256, 0, stream>>>(bufA, csr, offs2, dinv, b2, (float*)d_out, N);
}

// Round 8
// 351.567 us; speedup vs baseline: 1.5099x; 1.0503x over previous
//
#include <hip/hip_runtime.h>
#include <hip/hip_fp16.h>
#include <math.h>

// StackedGCN: N=100000, E=1600000, 128 -> 128 -> 128 -> 64, fp32 in/out.
// FP16 activation pipeline, fp32 MFMA accumulation, dinv prescaled in GEMM
// epilogue (operand-swapped GEMM). Aggregation: serial lane-group gather
// (r7: VALUBusy 43->17%, 60.6 us; now latency-bound at ~112 G granule/s
// with 4 loads in flight; c16 probe showed fabric sustains 133 G/s).
// Round-8: (1) agg128 MLP deepened 4->8 gathers in flight;
// (2) aggsm64 rewritten serial 8-lane-group (same win as r7 agg128);
// (3) prep_weights folded into scatter_bump, bcount zeroed by memsetAsync.
#define NN 100000
#define EE 1600000
#define NB2 782     // dst buckets: dst>>7 -> 128 nodes per bucket
#define BN 128      // nodes per bucket
#define NPART 512   // scatter_bump blocks
#define CAP 2560    // padded segment capacity (mean 2048, sd ~45 -> +11 sigma)

typedef __attribute__((ext_vector_type(8))) _Float16 half8;
typedef __attribute__((ext_vector_type(4))) float f32x4;
typedef __attribute__((ext_vector_type(4))) unsigned int u32x4;

__device__ inline unsigned short f2h(float x) {
    return __half_as_ushort(__float2half(x));
}
__device__ inline __half2 u2h2(unsigned u) {
    return __builtin_bit_cast(__half2, u);
}
__device__ inline unsigned h22u(__half2 h) {
    return __builtin_bit_cast(unsigned, h);
}

// ---------------- CSR build (weight prep folded in) ----------------

__global__ __launch_bounds__(256) void scatter_bump(const int* __restrict__ src,
                                                    const int* __restrict__ dst,
                                                    int* __restrict__ bcount,
                                                    int* __restrict__ P, int e,
                                                    const float* __restrict__ W0,
                                                    const float* __restrict__ W1,
                                                    const float* __restrict__ W2,
                                                    unsigned short* __restrict__ Wt0,
                                                    unsigned short* __restrict__ Wt1,
                                                    unsigned short* __restrict__ Wt2) {
    __shared__ int cnt[NB2];
    __shared__ int basep[NB2];
    __shared__ int cur[NB2];
    int t = threadIdx.x;
    {   // folded weight transpose+cast (first 160 blocks' worth of elements)
        int g = blockIdx.x * 256 + t;
        if (g < 16384) {
            int n = g >> 7, k = g & 127;
            Wt0[g] = f2h(W0[k * 128 + n]);
        } else if (g < 32768) {
            int i = g - 16384;
            int n = i >> 7, k = i & 127;
            Wt1[i] = f2h(W1[k * 128 + n]);
        } else if (g < 40960) {
            int i = g - 32768;
            int n = i >> 7, k = i & 127;
            Wt2[i] = f2h(W2[k * 64 + n]);
        }
    }
    for (int i = t; i < NB2; i += 256) { cnt[i] = 0; cur[i] = 0; }
    __syncthreads();
    int chunk = (e + NPART - 1) / NPART;
    int b0 = blockIdx.x * chunk, b1 = min(e, b0 + chunk);
    for (int i = b0 + t; i < b1; i += 256)
        atomicAdd(&cnt[dst[i] >> 7], 1);
    __syncthreads();
    for (int i = t; i < NB2; i += 256) {
        int c = cnt[i];
        basep[i] = c ? atomicAdd(&bcount[i], c) : 0;
    }
    __syncthreads();
    for (int i = b0 + t; i < b1; i += 256) {  // second read is L2-hot
        int d = dst[i];
        int b = d >> 7;
        int p = basep[b] + atomicAdd(&cur[b], 1);
        P[(size_t)b * CAP + p] = (src[i] << 7) | (d & 127);  // src<2^17: 24 bits
    }
}

__global__ __launch_bounds__(256) void bucket_build(const int* __restrict__ P,
                                                    const int* __restrict__ bcount,
                                                    int2* __restrict__ offs2,
                                                    float* __restrict__ dinv,
                                                    int* __restrict__ csr, int n) {
    __shared__ int cnt[BN];
    __shared__ int sc[BN];
    __shared__ int cur[BN];
    __shared__ int stage[CAP];
    int b = blockIdx.x, t = threadIdx.x;
    int base = b * CAP;
    int count = bcount[b];
    if (t < BN) cnt[t] = 0;
    __syncthreads();
    for (int i = t; i < count; i += 256)
        atomicAdd(&cnt[P[base + i] & 127], 1);
    __syncthreads();
    int v = 0;
    if (t < BN) {
        v = cnt[t];
        sc[t] = v;
    }
    for (int d = 1; d < BN; d <<= 1) {
        __syncthreads();
        int x = (t < BN && t >= d) ? sc[t - d] : 0;
        __syncthreads();
        if (t < BN) sc[t] += x;
    }
    __syncthreads();
    if (t < BN) {
        int myoff = sc[t] - v;
        int node = b * BN + t;
        if (node < n) {
            offs2[node] = make_int2(base + myoff, base + myoff + v);
            dinv[node] = 1.0f / sqrtf((float)(v + 1));  // +1 self-loop
        }
        cur[t] = myoff;
    }
    __syncthreads();
    for (int i = t; i < count; i += 256) {  // second read L2-hot
        int pe = P[base + i];
        int p = atomicAdd(&cur[pe & 127], 1);
        stage[p] = ((unsigned)pe) >> 7;     // p < count <= CAP always
    }
    __syncthreads();
    for (int i = t; i < count; i += 256) csr[base + i] = stage[i];
}

// ---------------- MFMA GEMM (f16) + dinv-prescale epilogue ----------------
// Operand swap: A := W-tile (LDS), B := X rows (global, no staging).
template <bool F32>
__device__ inline half8 load_xrow(const void* A, int row, int col, int nrows) {
    if (row >= nrows) {
        u32x4 z = {0u, 0u, 0u, 0u};
        return __builtin_bit_cast(half8, z);
    }
    if (F32) {
        const float* p = (const float*)A + (size_t)row * 128 + col;
        float4 v0 = *(const float4*)p;
        float4 v1 = *(const float4*)(p + 4);
        u32x4 u;
        u.x = h22u(__floats2half2_rn(v0.x, v0.y));
        u.y = h22u(__floats2half2_rn(v0.z, v0.w));
        u.z = h22u(__floats2half2_rn(v1.x, v1.y));
        u.w = h22u(__floats2half2_rn(v1.z, v1.w));
        return __builtin_bit_cast(half8, u);
    } else {
        const unsigned short* p = (const unsigned short*)A + (size_t)row * 128 + col;
        u32x4 u = *(const u32x4*)p;
        return __builtin_bit_cast(half8, u);
    }
}

template <int DOUT, bool A_IS_F32>
__global__ __launch_bounds__(256) void gemm_mfma(const void* __restrict__ Aptr,
                                                 const unsigned short* __restrict__ Wt,
                                                 const float* __restrict__ dinv,
                                                 unsigned short* __restrict__ Y, int nrows) {
    constexpr int KP = 136;
    constexpr int NT = DOUT / 16;
    __shared__ unsigned short sB[DOUT * KP];
    const int row0 = blockIdx.x * 128;
    const int tid = threadIdx.x;

    for (int i = tid; i < DOUT * 16; i += 256) {
        int n = i >> 4, c = (i & 15) * 8;
        uint4 v = *(const uint4*)(Wt + n * 128 + c);
        *(uint4*)(&sB[n * KP + c]) = v;
    }
    __syncthreads();

    const int wave = tid >> 6;
    const int lane = tid & 63;
    const int m0 = lane & 15;
    const int kq = (lane >> 4) * 8;
    const int xr0 = row0 + wave * 32 + m0;   // B-operand (X) rows
    const int xr1 = xr0 + 16;

    f32x4 acc[2][NT];
#pragma unroll
    for (int rt = 0; rt < 2; ++rt)
#pragma unroll
        for (int t = 0; t < NT; ++t) acc[rt][t] = (f32x4){0.f, 0.f, 0.f, 0.f};

#pragma unroll
    for (int k0 = 0; k0 < 128; k0 += 32) {
        half8 b0 = load_xrow<A_IS_F32>(Aptr, xr0, k0 + kq, nrows);
        half8 b1 = load_xrow<A_IS_F32>(Aptr, xr1, k0 + kq, nrows);
#pragma unroll
        for (int t = 0; t < NT; ++t) {
            half8 aW = *(const half8*)(&sB[(t * 16 + m0) * KP + k0 + kq]);
            acc[0][t] = __builtin_amdgcn_mfma_f32_16x16x32_f16(aW, b0, acc[0][t], 0, 0, 0);
            acc[1][t] = __builtin_amdgcn_mfma_f32_16x16x32_f16(aW, b1, acc[1][t], 0, 0, 0);
        }
    }

    // D layout: col(lane&15) = X-row within 16-block, row((lane>>4)*4+r) = out-feature
#pragma unroll
    for (int rt = 0; rt < 2; ++rt) {
        int xrow = row0 + wave * 32 + rt * 16 + m0;
        if (xrow < nrows) {
            float dv = dinv[xrow];
#pragma unroll
            for (int t = 0; t < NT; ++t) {
                uint2 o;
                o.x = h22u(__floats2half2_rn(acc[rt][t][0] * dv, acc[rt][t][1] * dv));
                o.y = h22u(__floats2half2_rn(acc[rt][t][2] * dv, acc[rt][t][3] * dv));
                *(uint2*)(Y + (size_t)xrow * DOUT + t * 16 + (lane >> 4) * 4) = o;
            }
        }
    }
}

// ---------------- aggregation D=128: serial 16-lane-group, 8 gathers in flight --------
__global__ __launch_bounds__(256) void agg128_f16(const unsigned short* __restrict__ Xp,
                                                  const int* __restrict__ csr,
                                                  const int2* __restrict__ offs2,
                                                  const float* __restrict__ dinv,
                                                  const float* __restrict__ bias,
                                                  unsigned short* __restrict__ Y, int n) {
    const int tid = threadIdx.x;
    const int node = blockIdx.x * 16 + (tid >> 4);
    if (node >= n) return;
    const int l = tid & 15;
    const unsigned short* __restrict__ Xl = Xp + l * 8;

    int2 se = offs2[node];
    int s = se.x, deg = se.y - se.x;
    const __half2 hz = __floats2half2_rn(0.f, 0.f);
    __half2 aA0 = hz, aA1 = hz, aA2 = hz, aA3 = hz;
    __half2 aB0 = hz, aB1 = hz, aB2 = hz, aB3 = hz;
    int j = 0;
    for (; j + 8 <= deg; j += 8) {   // 8 gathers in flight, uniform csr reads
        int i0 = csr[s + j],     i1 = csr[s + j + 1], i2 = csr[s + j + 2], i3 = csr[s + j + 3];
        int i4 = csr[s + j + 4], i5 = csr[s + j + 5], i6 = csr[s + j + 6], i7 = csr[s + j + 7];
        uint4 u0 = *(const uint4*)(Xl + (size_t)i0 * 128);
        uint4 u1 = *(const uint4*)(Xl + (size_t)i1 * 128);
        uint4 u2 = *(const uint4*)(Xl + (size_t)i2 * 128);
        uint4 u3 = *(const uint4*)(Xl + (size_t)i3 * 128);
        uint4 u4 = *(const uint4*)(Xl + (size_t)i4 * 128);
        uint4 u5 = *(const uint4*)(Xl + (size_t)i5 * 128);
        uint4 u6 = *(const uint4*)(Xl + (size_t)i6 * 128);
        uint4 u7 = *(const uint4*)(Xl + (size_t)i7 * 128);
        aA0 = __hadd2(aA0, u2h2(u0.x)); aA1 = __hadd2(aA1, u2h2(u0.y));
        aA2 = __hadd2(aA2, u2h2(u0.z)); aA3 = __hadd2(aA3, u2h2(u0.w));
        aB0 = __hadd2(aB0, u2h2(u1.x)); aB1 = __hadd2(aB1, u2h2(u1.y));
        aB2 = __hadd2(aB2, u2h2(u1.z)); aB3 = __hadd2(aB3, u2h2(u1.w));
        aA0 = __hadd2(aA0, u2h2(u2.x)); aA1 = __hadd2(aA1, u2h2(u2.y));
        aA2 = __hadd2(aA2, u2h2(u2.z)); aA3 = __hadd2(aA3, u2h2(u2.w));
        aB0 = __hadd2(aB0, u2h2(u3.x)); aB1 = __hadd2(aB1, u2h2(u3.y));
        aB2 = __hadd2(aB2, u2h2(u3.z)); aB3 = __hadd2(aB3, u2h2(u3.w));
        aA0 = __hadd2(aA0, u2h2(u4.x)); aA1 = __hadd2(aA1, u2h2(u4.y));
        aA2 = __hadd2(aA2, u2h2(u4.z)); aA3 = __hadd2(aA3, u2h2(u4.w));
        aB0 = __hadd2(aB0, u2h2(u5.x)); aB1 = __hadd2(aB1, u2h2(u5.y));
        aB2 = __hadd2(aB2, u2h2(u5.z)); aB3 = __hadd2(aB3, u2h2(u5.w));
        aA0 = __hadd2(aA0, u2h2(u6.x)); aA1 = __hadd2(aA1, u2h2(u6.y));
        aA2 = __hadd2(aA2, u2h2(u6.z)); aA3 = __hadd2(aA3, u2h2(u6.w));
        aB0 = __hadd2(aB0, u2h2(u7.x)); aB1 = __hadd2(aB1, u2h2(u7.y));
        aB2 = __hadd2(aB2, u2h2(u7.z)); aB3 = __hadd2(aB3, u2h2(u7.w));
    }
    for (; j + 4 <= deg; j += 4) {
        int i0 = csr[s + j], i1 = csr[s + j + 1], i2 = csr[s + j + 2], i3 = csr[s + j + 3];
        uint4 u0 = *(const uint4*)(Xl + (size_t)i0 * 128);
        uint4 u1 = *(const uint4*)(Xl + (size_t)i1 * 128);
        uint4 u2 = *(const uint4*)(Xl + (size_t)i2 * 128);
        uint4 u3 = *(const uint4*)(Xl + (size_t)i3 * 128);
        aA0 = __hadd2(aA0, u2h2(u0.x)); aA1 = __hadd2(aA1, u2h2(u0.y));
        aA2 = __hadd2(aA2, u2h2(u0.z)); aA3 = __hadd2(aA3, u2h2(u0.w));
        aB0 = __hadd2(aB0, u2h2(u1.x)); aB1 = __hadd2(aB1, u2h2(u1.y));
        aB2 = __hadd2(aB2, u2h2(u1.z)); aB3 = __hadd2(aB3, u2h2(u1.w));
        aA0 = __hadd2(aA0, u2h2(u2.x)); aA1 = __hadd2(aA1, u2h2(u2.y));
        aA2 = __hadd2(aA2, u2h2(u2.z)); aA3 = __hadd2(aA3, u2h2(u2.w));
        aB0 = __hadd2(aB0, u2h2(u3.x)); aB1 = __hadd2(aB1, u2h2(u3.y));
        aB2 = __hadd2(aB2, u2h2(u3.z)); aB3 = __hadd2(aB3, u2h2(u3.w));
    }
    for (; j < deg; ++j) {
        int i0 = csr[s + j];
        uint4 u = *(const uint4*)(Xl + (size_t)i0 * 128);
        aA0 = __hadd2(aA0, u2h2(u.x)); aA1 = __hadd2(aA1, u2h2(u.y));
        aA2 = __hadd2(aA2, u2h2(u.z)); aA3 = __hadd2(aA3, u2h2(u.w));
    }
    {   // self-loop row (prescaled); each lane adds its own feature slice
        uint4 u = *(const uint4*)(Xl + (size_t)node * 128);
        aB0 = __hadd2(aB0, u2h2(u.x)); aB1 = __hadd2(aB1, u2h2(u.y));
        aB2 = __hadd2(aB2, u2h2(u.z)); aB3 = __hadd2(aB3, u2h2(u.w));
    }
    float di = dinv[node];
    float4 bA = *(const float4*)(bias + l * 8);
    float4 bB = *(const float4*)(bias + l * 8 + 4);
    float2 fA, fB;
    fA = __half22float2(aA0); fB = __half22float2(aB0);
    float r0 = fA.x + fB.x, r1 = fA.y + fB.y;
    fA = __half22float2(aA1); fB = __half22float2(aB1);
    float r2 = fA.x + fB.x, r3 = fA.y + fB.y;
    fA = __half22float2(aA2); fB = __half22float2(aB2);
    float r4 = fA.x + fB.x, r5 = fA.y + fB.y;
    fA = __half22float2(aA3); fB = __half22float2(aB3);
    float r6 = fA.x + fB.x, r7 = fA.y + fB.y;
    r0 = fmaxf(fmaf(di, r0, bA.x), 0.f); r1 = fmaxf(fmaf(di, r1, bA.y), 0.f);
    r2 = fmaxf(fmaf(di, r2, bA.z), 0.f); r3 = fmaxf(fmaf(di, r3, bA.w), 0.f);
    r4 = fmaxf(fmaf(di, r4, bB.x), 0.f); r5 = fmaxf(fmaf(di, r5, bB.y), 0.f);
    r6 = fmaxf(fmaf(di, r6, bB.z), 0.f); r7 = fmaxf(fmaf(di, r7, bB.w), 0.f);
    uint4 o;
    o.x = h22u(__floats2half2_rn(r0, r1));
    o.y = h22u(__floats2half2_rn(r2, r3));
    o.z = h22u(__floats2half2_rn(r4, r5));
    o.w = h22u(__floats2half2_rn(r6, r7));
    *(uint4*)(Y + (size_t)node * 128 + l * 8) = o;
}

// ---------------- last layer D=64: serial 8-lane-group + log_softmax ----------------
// One 8-lane group per node (32 nodes/block). Lane l owns features l*8..+7,
// accumulates over all edges serially; softmax reduce = 3 shfl over group.
__global__ __launch_bounds__(256) void agg_softmax64_f16(const unsigned short* __restrict__ Xp,
                                                         const int* __restrict__ csr,
                                                         const int2* __restrict__ offs2,
                                                         const float* __restrict__ dinv,
                                                         const float* __restrict__ bias,
                                                         float* __restrict__ out, int n) {
    const int tid = threadIdx.x;
    const int node = blockIdx.x * 32 + (tid >> 3);
    if (node >= n) return;
    const int l = tid & 7;
    const unsigned short* __restrict__ Xl = Xp + l * 8;

    int2 se = offs2[node];
    int s = se.x, deg = se.y - se.x;
    const __half2 hz = __floats2half2_rn(0.f, 0.f);
    __half2 aA0 = hz, aA1 = hz, aA2 = hz, aA3 = hz;
    __half2 aB0 = hz, aB1 = hz, aB2 = hz, aB3 = hz;
    int j = 0;
    for (; j + 8 <= deg; j += 8) {   // 8 gathers in flight
        int i0 = csr[s + j],     i1 = csr[s + j + 1], i2 = csr[s + j + 2], i3 = csr[s + j + 3];
        int i4 = csr[s + j + 4], i5 = csr[s + j + 5], i6 = csr[s + j + 6], i7 = csr[s + j + 7];
        uint4 u0 = *(const uint4*)(Xl + (size_t)i0 * 64);
        uint4 u1 = *(const uint4*)(Xl + (size_t)i1 * 64);
        uint4 u2 = *(const uint4*)(Xl + (size_t)i2 * 64);
        uint4 u3 = *(const uint4*)(Xl + (size_t)i3 * 64);
        uint4 u4 = *(const uint4*)(Xl + (size_t)i4 * 64);
        uint4 u5 = *(const uint4*)(Xl + (size_t)i5 * 64);
        uint4 u6 = *(const uint4*)(Xl + (size_t)i6 * 64);
        uint4 u7 = *(const uint4*)(Xl + (size_t)i7 * 64);
        aA0 = __hadd2(aA0, u2h2(u0.x)); aA1 = __hadd2(aA1, u2h2(u0.y));
        aA2 = __hadd2(aA2, u2h2(u0.z)); aA3 = __hadd2(aA3, u2h2(u0.w));
        aB0 = __hadd2(aB0, u2h2(u1.x)); aB1 = __hadd2(aB1, u2h2(u1.y));
        aB2 = __hadd2(aB2, u2h2(u1.z)); aB3 = __hadd2(aB3, u2h2(u1.w));
        aA0 = __hadd2(aA0, u2h2(u2.x)); aA1 = __hadd2(aA1, u2h2(u2.y));
        aA2 = __hadd2(aA2, u2h2(u2.z)); aA3 = __hadd2(aA3, u2h2(u2.w));
        aB0 = __hadd2(aB0, u2h2(u3.x)); aB1 = __hadd2(aB1, u2h2(u3.y));
        aB2 = __hadd2(aB2, u2h2(u3.z)); aB3 = __hadd2(aB3, u2h2(u3.w));
        aA0 = __hadd2(aA0, u2h2(u4.x)); aA1 = __hadd2(aA1, u2h2(u4.y));
        aA2 = __hadd2(aA2, u2h2(u4.z)); aA3 = __hadd2(aA3, u2h2(u4.w));
        aB0 = __hadd2(aB0, u2h2(u5.x)); aB1 = __hadd2(aB1, u2h2(u5.y));
        aB2 = __hadd2(aB2, u2h2(u5.z)); aB3 = __hadd2(aB3, u2h2(u5.w));
        aA0 = __hadd2(aA0, u2h2(u6.x)); aA1 = __hadd2(aA1, u2h2(u6.y));
        aA2 = __hadd2(aA2, u2h2(u6.z)); aA3 = __hadd2(aA3, u2h2(u6.w));
        aB0 = __hadd2(aB0, u2h2(u7.x)); aB1 = __hadd2(aB1, u2h2(u7.y));
        aB2 = __hadd2(aB2, u2h2(u7.z)); aB3 = __hadd2(aB3, u2h2(u7.w));
    }
    for (; j < deg; ++j) {
        int i0 = csr[s + j];
        uint4 u = *(const uint4*)(Xl + (size_t)i0 * 64);
        aA0 = __hadd2(aA0, u2h2(u.x)); aA1 = __hadd2(aA1, u2h2(u.y));
        aA2 = __hadd2(aA2, u2h2(u.z)); aA3 = __hadd2(aA3, u2h2(u.w));
    }
    {   // self-loop
        uint4 u = *(const uint4*)(Xl + (size_t)node * 64);
        aB0 = __hadd2(aB0, u2h2(u.x)); aB1 = __hadd2(aB1, u2h2(u.y));
        aB2 = __hadd2(aB2, u2h2(u.z)); aB3 = __hadd2(aB3, u2h2(u.w));
    }
    float di = dinv[node];
    float4 bA = *(const float4*)(bias + l * 8);
    float4 bB = *(const float4*)(bias + l * 8 + 4);
    float2 fA, fB;
    fA = __half22float2(aA0); fB = __half22float2(aB0);
    float r0 = fA.x + fB.x, r1 = fA.y + fB.y;
    fA = __half22float2(aA1); fB = __half22float2(aB1);
    float r2 = fA.x + fB.x, r3 = fA.y + fB.y;
    fA = __half22float2(aA2); fB = __half22float2(aB2);
    float r4 = fA.x + fB.x, r5 = fA.y + fB.y;
    fA = __half22float2(aA3); fB = __half22float2(aB3);
    float r6 = fA.x + fB.x, r7 = fA.y + fB.y;
    r0 = fmaf(di, r0, bA.x); r1 = fmaf(di, r1, bA.y);
    r2 = fmaf(di, r2, bA.z); r3 = fmaf(di, r3, bA.w);
    r4 = fmaf(di, r4, bB.x); r5 = fmaf(di, r5, bB.y);
    r6 = fmaf(di, r6, bB.z); r7 = fmaf(di, r7, bB.w);
    // log_softmax over 64 features: per-lane max/sum of 8, 3 shfl over group
    float m = fmaxf(fmaxf(fmaxf(r0, r1), fmaxf(r2, r3)), fmaxf(fmaxf(r4, r5), fmaxf(r6, r7)));
    m = fmaxf(m, __shfl_xor(m, 1));
    m = fmaxf(m, __shfl_xor(m, 2));
    m = fmaxf(m, __shfl_xor(m, 4));
    float ssum = __expf(r0 - m) + __expf(r1 - m) + __expf(r2 - m) + __expf(r3 - m) +
                 __expf(r4 - m) + __expf(r5 - m) + __expf(r6 - m) + __expf(r7 - m);
    ssum += __shfl_xor(ssum, 1);
    ssum += __shfl_xor(ssum, 2);
    ssum += __shfl_xor(ssum, 4);
    float lg = m + __logf(ssum);
    float4 o0 = make_float4(r0 - lg, r1 - lg, r2 - lg, r3 - lg);
    float4 o1 = make_float4(r4 - lg, r5 - lg, r6 - lg, r7 - lg);
    *(float4*)(out + (size_t)node * 64 + l * 8) = o0;
    *(float4*)(out + (size_t)node * 64 + l * 8 + 4) = o1;
}

// ---------------- launcher ----------------

extern "C" void kernel_launch(void* const* d_in, const int* in_sizes, int n_in,
                              void* d_out, int out_size, void* d_ws, size_t ws_size,
                              hipStream_t stream) {
    const int* edges = (const int*)d_in[0];
    const float* feat = (const float*)d_in[1];
    const float* W0 = (const float*)d_in[2];
    const float* b0 = (const float*)d_in[3];
    const float* W1 = (const float*)d_in[4];
    const float* b1 = (const float*)d_in[5];
    const float* W2 = (const float*)d_in[6];
    const float* b2 = (const float*)d_in[7];

    const int N = NN;
    const int E = EE;

    char* ws = (char*)d_ws;
    int* bcount = (int*)ws;                       // NB2
    int2* offs2 = (int2*)(bcount + ((NB2 + 1) & ~1));  // N (8B aligned)
    float* dinv = (float*)(offs2 + N);            // N
    int* P = (int*)(dinv + N);                    // NB2*CAP (packed src<<7|dst&127)
    int* csr = P + (size_t)NB2 * CAP;             // NB2*CAP (src only)
    unsigned short* Wt0 = (unsigned short*)(csr + (size_t)NB2 * CAP);  // 16384
    unsigned short* Wt1 = Wt0 + 16384;            // 16384
    unsigned short* Wt2 = Wt1 + 16384;            // 8192
    size_t off = (size_t)((char*)(Wt2 + 8192) - ws);
    off = (off + 255) & ~(size_t)255;
    unsigned short* bufA = (unsigned short*)(ws + off);  // N*128 fp16
    unsigned short* bufB = bufA + (size_t)N * 128;       // N*128 fp16

    const int* esrc = edges;
    const int* edst = edges + E;

    // CSR build (bcount zeroed by async memset; weight prep folded into scatter)
    hipMemsetAsync(bcount, 0, NB2 * sizeof(int), stream);
    scatter_bump<<<NPART, 256, 0, stream>>>(esrc, edst, bcount, P, E,
                                            W0, W1, W2, Wt0, Wt1, Wt2);
    bucket_build<<<NB2, 256, 0, stream>>>(P, bcount, offs2, dinv, csr, N);

    const int gemmBlocks = (N + 127) / 128;   // 782
    const int agg128Blocks = (N + 15) / 16;   // 6250
    const int aggsmBlocks = (N + 31) / 32;    // 3125

    // layer 0
    gemm_mfma<128, true><<<gemmBlocks, 256, 0, stream>>>(feat, Wt0, dinv, bufA, N);
    agg128_f16<<<agg128Blocks, 256, 0, stream>>>(bufA, csr, offs2, dinv, b0, bufB, N);
    // layer 1
    gemm_mfma<128, false><<<gemmBlocks, 256, 0, stream>>>(bufB, Wt1, dinv, bufA, N);
    agg128_f16<<<agg128Blocks, 256, 0, stream>>>(bufA, csr, offs2, dinv, b1, bufB, N);
    // layer 2 + log_softmax
    gemm_mfma<64, false><<<gemmBlocks, 256, 0, stream>>>(bufB, Wt2, dinv, bufA, N);
    agg_softmax64_f16<<<aggsmBlocks, 256, 0, stream>>>(bufA, csr, offs2, dinv, b2, (float*)d_out, N);
}